// Round 7
// baseline (468.043 us; speedup 1.0000x reference)
//
#include <hip/hip_runtime.h>
#include <stdint.h>

typedef unsigned short u16;
typedef __bf16 bf16x8 __attribute__((ext_vector_type(8)));
typedef float f32x4 __attribute__((ext_vector_type(4)));

#define DEVINL static __device__ __forceinline__

// fp32 -> bf16 round-to-nearest-even
DEVINL u16 f2bf(float f) {
  uint32_t u = __builtin_bit_cast(uint32_t, f);
  u += 0x7fffu + ((u >> 16) & 1u);
  return (u16)(u >> 16);
}

// pack two fp32 -> bf16x2 dword (round-half-up: +0x8000 then take hi16)
DEVINL uint32_t pack_bf2(float f0, float f1) {
  uint32_t u0 = __builtin_bit_cast(uint32_t, f0) + 0x8000u;
  uint32_t u1 = __builtin_bit_cast(uint32_t, f1) + 0x8000u;
  return __builtin_amdgcn_perm(u1, u0, 0x07060302u);  // [u1.hi16, u0.hi16]
}

DEVINL bf16x8 ld_frag(const u16* p) { return *(const bf16x8*)p; }

DEVINL void gld_lds16(const void* g, void* l) {
  __builtin_amdgcn_global_load_lds((const __attribute__((address_space(1))) void*)g,
                                   (__attribute__((address_space(3))) void*)l, 16, 0, 0);
}

DEVINL int swz4(int r) { return (r & 3) ^ ((r >> 2) & 3); }

// T1: bijective XCD-chunked swizzle, 128-row tiles (body2 grids, nwg % 8 == 0).
DEVINL void xcd_tile(int& tm, int& tn) {
  const int gx = gridDim.x;
  const int flat = blockIdx.x + gx * blockIdx.y;
  const int q = (gx * gridDim.y) >> 3;
  const int wg = (flat & 7) * q + (flat >> 3);
  tn = (wg % gx) * 128;
  tm = (wg / gx) * 128;
}

// T1 for 256-row tiles (bodyW grids).
DEVINL void xcd_tile_wide(int& tm, int& tn) {
  const int gx = gridDim.x;
  const int flat = blockIdx.x + gx * blockIdx.y;
  const int q = (gx * gridDim.y) >> 3;
  const int wg = (flat & 7) * q + (flat >> 3);
  tn = (wg % gx) * 128;
  tm = (wg / gx) * 256;
}

// ---------------------------------------------------------------------------
// Weight convert+transpose: W fp32 (K,N) row-major -> Wt bf16 (N,K) row-major
// ---------------------------------------------------------------------------
__global__ __launch_bounds__(256)
void transpose_bf16(const float* __restrict__ W, u16* __restrict__ Wt, int K, int N) {
  __shared__ float tile[32][33];
  const int n0 = blockIdx.x * 32, k0 = blockIdx.y * 32;
  const int tx = threadIdx.x, ty = threadIdx.y;  // (32,8)
#pragma unroll
  for (int i = 0; i < 32; i += 8)
    tile[ty + i][tx] = W[(size_t)(k0 + ty + i) * N + n0 + tx];
  __syncthreads();
#pragma unroll
  for (int i = 0; i < 32; i += 8)
    Wt[(size_t)(n0 + ty + i) * K + k0 + tx] = f2bf(tile[tx][ty + i]);
}

// ---------------------------------------------------------------------------
// LayerNorm: fp32 (rows,1024) -> bf16, single pass (E[x^2]-mu^2), eps=1e-5
// ---------------------------------------------------------------------------
__global__ __launch_bounds__(256)
void ln_kernel(const float* __restrict__ x, const float* __restrict__ g,
               const float* __restrict__ b, u16* __restrict__ out) {
  __shared__ float red[8];
  const size_t row = blockIdx.x;
  const int tid = threadIdx.x;
  float4 v = ((const float4*)(x + row * 1024))[tid];
  float s = v.x + v.y + v.z + v.w;
  float s2 = v.x * v.x + v.y * v.y + v.z * v.z + v.w * v.w;
#pragma unroll
  for (int o = 32; o; o >>= 1) { s += __shfl_down(s, o); s2 += __shfl_down(s2, o); }
  const int w = tid >> 6;
  if ((tid & 63) == 0) { red[w * 2] = s; red[w * 2 + 1] = s2; }
  __syncthreads();
  const float S = red[0] + red[2] + red[4] + red[6];
  const float S2 = red[1] + red[3] + red[5] + red[7];
  const float mu = S * (1.f / 1024.f);
  const float var = S2 * (1.f / 1024.f) - mu * mu;
  const float rstd = rsqrtf(var + 1e-5f);
  float4 gv = ((const float4*)g)[tid];
  float4 bv = ((const float4*)b)[tid];
  ushort4 o;
  o.x = f2bf((v.x - mu) * rstd * gv.x + bv.x);
  o.y = f2bf((v.y - mu) * rstd * gv.y + bv.y);
  o.z = f2bf((v.z - mu) * rstd * gv.z + bv.z);
  o.w = f2bf((v.w - mu) * rstd * gv.w + bv.w);
  ((ushort4*)(out + row * 1024))[tid] = o;
}

// ---------------------------------------------------------------------------
// Shared epilogue: C row/col scatter with fused ops.
// ---------------------------------------------------------------------------
enum { EPI_KQV = 0, EPI_RESID = 1, EPI_GELU = 2, EPI_ADD = 3 };

template <int EPI>
DEVINL void gemm_epilogue(f32x4 (&acc)[4][4], const float* __restrict__ bias,
                          void* __restrict__ outp, const float* __restrict__ resid,
                          int N, int tm, int tn, int mh, int nh, int q4, int c) {
#pragma unroll
  for (int mt = 0; mt < 4; ++mt) {
#pragma unroll
    for (int nt = 0; nt < 4; ++nt) {
      const int col = tn + nh + nt * 16 + c;
      const float bcol = bias[col];
#pragma unroll
      for (int rg = 0; rg < 4; ++rg) {
        const int row = tm + mh + mt * 16 + q4 * 4 + rg;
        float val = acc[mt][nt][rg] + bcol;
        if constexpr (EPI == EPI_KQV) {
          // scatter to per-head layout [b,h][s][...]; s: 0=k (flash-Q, pre-scaled
          // by 0.125*log2e for exp2-domain softmax), 1=q (t,d), 2=v stored (d,t)
          const int bb = row >> 10, t = row & 1023;
          const int s = col >> 10, rem = col & 1023;
          const int hh = rem >> 6, d = rem & 63;
          if (s == 0) val *= 0.18033688011112042f;  // 0.125 * log2(e)
          const size_t base = ((size_t)((bb * 16 + hh) * 3 + s)) << 16;
          const size_t idx = (s == 2) ? base + (size_t)d * 1024 + t : base + (size_t)t * 64 + d;
          ((u16*)outp)[idx] = f2bf(val);
        } else if constexpr (EPI == EPI_RESID) {
          const size_t idx = (size_t)row * 1024 + col;
          ((float*)outp)[idx] = val + resid[idx];
        } else if constexpr (EPI == EPI_GELU) {
          // tanh-approx GELU via single exp2: x*sigmoid(1.5957691(x+0.044715x^3))
          const float x2 = val * val;
          const float t = __builtin_fmaf(x2, -0.102952445f, -2.30221235f);  // *log2e folded
          const float e = __builtin_amdgcn_exp2f(val * t);
          const float ge = val * __builtin_amdgcn_rcpf(1.0f + e);
          ((u16*)outp)[(size_t)row * N + col] = f2bf(ge);
        } else {  // EPI_ADD: accumulate into fp32 out (sole writer)
          const size_t idx = (size_t)row * 1024 + col;
          ((float*)outp)[idx] += val;
        }
      }
    }
  }
}

// ---------------------------------------------------------------------------
// GEMM body2 (128x128, 4 waves, 2-buffer): for grids with >=4 blocks/CU of
// TLP (kqv). Round-4-verified.
// ---------------------------------------------------------------------------
template <int EPI>
DEVINL void gemm_body2(const u16* __restrict__ A, const u16* __restrict__ Bt,
                       const float* __restrict__ bias, void* __restrict__ outp,
                       const float* __restrict__ resid, int M, int N, int K,
                       int tm, int tn) {
  __shared__ alignas(16) u16 sA[2][128 * 32];
  __shared__ alignas(16) u16 sB[2][128 * 32];
  const int tid = threadIdx.x;
  const int w = tid >> 6, l = tid & 63;
  const int q4 = l >> 4, c = l & 15;
  const int mh = (w >> 1) * 64, nh = (w & 1) * 64;
  const int cg8 = (q4 ^ swz4(c)) * 8;

  f32x4 acc[4][4] = {};

  const int srow = l >> 2;
  const int scol = ((l & 3) ^ swz4(srow)) * 8;
  const u16* gA0 = A + (size_t)(tm + (w * 2) * 16 + srow) * K + scol;
  const u16* gA1 = A + (size_t)(tm + (w * 2 + 1) * 16 + srow) * K + scol;
  const u16* gB0 = Bt + (size_t)(tn + (w * 2) * 16 + srow) * K + scol;
  const u16* gB1 = Bt + (size_t)(tn + (w * 2 + 1) * 16 + srow) * K + scol;
  const int cA0 = (w * 2) * 512, cA1 = (w * 2 + 1) * 512;

  const int nIters = K / 32;
#define STAGE2(buf, k0)                         \
  do {                                          \
    gld_lds16(gA0 + (k0), &sA[buf][cA0]);       \
    gld_lds16(gA1 + (k0), &sA[buf][cA1]);       \
    gld_lds16(gB0 + (k0), &sB[buf][cA0]);       \
    gld_lds16(gB1 + (k0), &sB[buf][cA1]);       \
  } while (0)

  STAGE2(0, 0);
  for (int i = 0; i < nIters; ++i) {
    const int cur = i & 1;
    asm volatile("s_waitcnt vmcnt(0)" ::: "memory");  // buf[cur] staged
    __syncthreads();  // all waves done reading buf[cur^1] (iter i-1) + see stage
    if (i + 1 < nIters) STAGE2(cur ^ 1, (i + 1) * 32);  // overlaps compute below
    const u16* bA = sA[cur];
    const u16* bB = sB[cur];
    bf16x8 af[4], bfv[4];
#pragma unroll
    for (int mt = 0; mt < 4; ++mt) af[mt] = ld_frag(bA + (mh + mt * 16 + c) * 32 + cg8);
#pragma unroll
    for (int nt = 0; nt < 4; ++nt) bfv[nt] = ld_frag(bB + (nh + nt * 16 + c) * 32 + cg8);
#pragma unroll
    for (int mt = 0; mt < 4; ++mt)
#pragma unroll
      for (int nt = 0; nt < 4; ++nt)
        acc[mt][nt] = __builtin_amdgcn_mfma_f32_16x16x32_bf16(af[mt], bfv[nt], acc[mt][nt], 0, 0, 0);
  }
#undef STAGE2
  gemm_epilogue<EPI>(acc, bias, outp, resid, N, tm, tn, mh, nh, q4, c);
}

// ---------------------------------------------------------------------------
// GEMM body WIDE (256x128 tile, 8 waves, BK=64, 3-deep ring, 144KB LDS).
// Round-5 loop restored verbatim (round-6 phase-split regressed: more barriers
// per MFMA without enough interleave benefit). Counted vmcnt(6), single
// barrier-pair per K-step, conflicts=0 (row-XOR swizzle both-sides).
// Requires K/64 >= 3 and grid nwg % 8 == 0. Best at <=2 blocks-rounds/CU.
// ---------------------------------------------------------------------------
template <int EPI>
DEVINL void gemm_bodyW(const u16* __restrict__ A, const u16* __restrict__ Bt,
                       const float* __restrict__ bias, void* __restrict__ outp,
                       const float* __restrict__ resid, int N, int K,
                       int tm, int tn) {
  __shared__ alignas(16) u16 sT[3][48 * 512];
  const int tid = threadIdx.x;
  const int w = tid >> 6, l = tid & 63;
  const int q4 = l >> 4, c = l & 15;
  const int mh = (w >> 1) * 64, nh = (w & 1) * 64;  // 4M x 2N waves of 64x64

  f32x4 acc[4][4] = {};

  const int lr = l >> 3;
  const int lc = ((l & 7) ^ lr) * 8;  // pre-swizzled global k-offset (elems)
  const u16* gA[4];
  const u16* gB[2];
#pragma unroll
  for (int j = 0; j < 4; ++j) gA[j] = A + (size_t)(tm + 32 * w + j * 8 + lr) * K + lc;
#pragma unroll
  for (int j = 0; j < 2; ++j) gB[j] = Bt + (size_t)(tn + 16 * w + j * 8 + lr) * K + lc;

  auto stageW = [&](int buf, int k0) {
#pragma unroll
    for (int j = 0; j < 4; ++j) gld_lds16(gA[j] + k0, &sT[buf][(4 * w + j) * 512]);
#pragma unroll
    for (int j = 0; j < 2; ++j) gld_lds16(gB[j] + k0, &sT[buf][(32 + 2 * w + j) * 512]);
  };

  auto computeW = [&](int cur) {
    const u16* bufA = sT[cur];
    const u16* bufB = sT[cur] + 32 * 512;
#pragma unroll
    for (int kh = 0; kh < 2; ++kh) {
      bf16x8 af[4], bfv[4];
#pragma unroll
      for (int mt = 0; mt < 4; ++mt) {
        const int row = mh + mt * 16 + c;
        af[mt] = ld_frag(bufA + row * 64 + ((kh * 4 + q4) ^ (c & 7)) * 8);
      }
#pragma unroll
      for (int nt = 0; nt < 4; ++nt) {
        const int row = nh + nt * 16 + c;
        bfv[nt] = ld_frag(bufB + row * 64 + ((kh * 4 + q4) ^ (c & 7)) * 8);
      }
      __builtin_amdgcn_s_setprio(1);
#pragma unroll
      for (int mt = 0; mt < 4; ++mt)
#pragma unroll
        for (int nt = 0; nt < 4; ++nt)
          acc[mt][nt] = __builtin_amdgcn_mfma_f32_16x16x32_bf16(af[mt], bfv[nt], acc[mt][nt], 0, 0, 0);
      __builtin_amdgcn_s_setprio(0);
    }
  };

  const int nI = K / 64;  // >= 3 required
  stageW(0, 0);
  stageW(1, 64);
  int bc = 0;  // buffer being computed; stage target = (bc+2)%3
  int i = 0;
  for (; i < nI - 1; ++i) {
    asm volatile("s_waitcnt vmcnt(6)" ::: "memory");
    __builtin_amdgcn_s_barrier();
    asm volatile("" ::: "memory");
    if (i + 2 < nI) {
      const int tgt = (bc >= 1) ? bc - 1 : 2;  // (bc+2)%3
      stageW(tgt, (i + 2) * 64);
    }
    computeW(bc);
    bc = (bc < 2) ? bc + 1 : 0;
  }
  asm volatile("s_waitcnt vmcnt(0)" ::: "memory");
  __builtin_amdgcn_s_barrier();
  asm volatile("" ::: "memory");
  computeW(bc);

  gemm_epilogue<EPI>(acc, bias, outp, resid, N, tm, tn, mh, nh, q4, c);
}

// ---- wrappers (distinct names so rocprof attributes per GEMM instance) ----
// kqv: body2 (1536 blocks = 6/CU TLP beats bodyW's 3 fill rounds — r5 lesson)
__global__ __launch_bounds__(256)
void gemm_kqv(const u16* __restrict__ A, const u16* __restrict__ Bt,
              const float* __restrict__ bias, u16* __restrict__ outp,
              int M, int N, int K) {
  int tm, tn;
  xcd_tile(tm, tn);
  gemm_body2<EPI_KQV>(A, Bt, bias, outp, nullptr, M, N, K, tm, tn);
}

__global__ __launch_bounds__(512)
void gemm_gelu(const u16* __restrict__ A, const u16* __restrict__ Bt,
               const float* __restrict__ bias, u16* __restrict__ outp,
               int M, int N, int K) {
  int tm, tn;
  xcd_tile_wide(tm, tn);
  gemm_bodyW<EPI_GELU>(A, Bt, bias, outp, nullptr, N, K, tm, tn);
}

__global__ __launch_bounds__(512)
void gemm_resid(const u16* __restrict__ A, const u16* __restrict__ Bt,
                const float* __restrict__ bias, float* __restrict__ outp,
                const float* __restrict__ resid, int M, int N, int K) {
  int tm, tn;
  xcd_tile_wide(tm, tn);
  gemm_bodyW<EPI_RESID>(A, Bt, bias, outp, resid, N, K, tm, tn);
}

__global__ __launch_bounds__(512)
void gemm_add(const u16* __restrict__ A, const u16* __restrict__ Bt,
              const float* __restrict__ bias, float* __restrict__ outp,
              int M, int N, int K) {
  int tm, tn;
  xcd_tile_wide(tm, tn);
  gemm_bodyW<EPI_ADD>(A, Bt, bias, outp, nullptr, N, K, tm, tn);
}

// ---------------------------------------------------------------------------
// Flash attention, causal, fixed-max softmax in exp2 domain.
// T14 async-stage split added this round: registers hold tile jt's K/V while
// tile jt+1's global loads are issued right after the publish barrier — HBM/L2
// latency drains under QK^T/softmax/PV compute; ds_write happens at the top of
// the next iteration (compiler inserts the vmcnt wait there). Same barrier
// structure as before; +16 VGPR.
// ---------------------------------------------------------------------------
__global__ __launch_bounds__(256)
void attn_kernel(const u16* __restrict__ kqv, u16* __restrict__ outp) {
  constexpr int LS = 72;  // padded stride: 144B rows, 16B aligned, 2-way max conflicts
  __shared__ alignas(16) u16 sP[64 * LS];  // holds Q tile at start, then P (aliased)
  __shared__ alignas(16) u16 sK[64 * LS];
  __shared__ alignas(16) u16 sV[64 * LS];  // V^T tile: row=d, col=j
  const int bh = blockIdx.x;
  const int it = (int)gridDim.y - 1 - (int)blockIdx.y;  // longest blocks dispatch first
  const int tid = threadIdx.x;
  const int w = tid >> 6, l = tid & 63, q4 = l >> 4, c = l & 15;
  const int il = w * 16 + c;  // this lane's i-row within the 64-row tile
  const size_t hb = (size_t)bh * 3 * 65536;
  const u16* qbase = kqv + hb;               // flash-Q (T,D), pre-scaled
  const u16* kbase = kqv + hb + 65536;       // flash-K (T,D)
  const u16* vbase = kqv + hb + 2 * 65536;   // V^T (D,T)

  // stage Q tile into sP (aliased; consumed once after first barrier)
  const int sr = tid >> 3, sc = (tid & 7) * 8;        // staging row/col A
  const int sr2 = sr + 32;                            // staging row B
  *(int4*)&sP[sr * LS + sc] = *(const int4*)(qbase + (size_t)(it * 64 + sr) * 64 + sc);
  *(int4*)&sP[sr2 * LS + sc] = *(const int4*)(qbase + (size_t)(it * 64 + sr2) * 64 + sc);

  f32x4 oacc[4] = {};   // O^T: oacc[dt][rg] = O[i=il][d=dt*16+q4*4+rg]
  float lsum = 0.f;     // per-lane partial row-sum for row i=il
  bf16x8 bq0, bq1;      // loop-invariant Q B-frags

  // T14: preload tile 0 into regs
  int4 rk0 = *(const int4*)(kbase + (size_t)sr * 64 + sc);
  int4 rk1 = *(const int4*)(kbase + (size_t)sr2 * 64 + sc);
  int4 rv0 = *(const int4*)(vbase + (size_t)sr * 1024 + sc);
  int4 rv1 = *(const int4*)(vbase + (size_t)sr2 * 1024 + sc);

  for (int jt = 0; jt <= it; ++jt) {
    if (jt) __syncthreads();  // prior iter's sK/sV reads done before overwrite
    *(int4*)&sK[sr * LS + sc] = rk0;
    *(int4*)&sK[sr2 * LS + sc] = rk1;
    *(int4*)&sV[sr * LS + sc] = rv0;
    *(int4*)&sV[sr2 * LS + sc] = rv1;
    __syncthreads();
    if (jt < it) {  // issue next tile's loads; they drain under the compute below
      rk0 = *(const int4*)(kbase + (size_t)((jt + 1) * 64 + sr) * 64 + sc);
      rk1 = *(const int4*)(kbase + (size_t)((jt + 1) * 64 + sr2) * 64 + sc);
      rv0 = *(const int4*)(vbase + (size_t)sr * 1024 + (jt + 1) * 64 + sc);
      rv1 = *(const int4*)(vbase + (size_t)sr2 * 1024 + (jt + 1) * 64 + sc);
    }
    if (jt == 0) {  // Q frags: B[k=d][n=i]: lane reads fQ[i=il][d=q4*8..]
      bq0 = ld_frag(sP + il * LS + q4 * 8);
      bq1 = ld_frag(sP + il * LS + 32 + q4 * 8);
    }

    // S^T = fK @ fQ^T: st[nt] row j=nt*16+q4*4+rg, col i=il (values in log2 domain)
    f32x4 st[4] = {};
#pragma unroll
    for (int nt = 0; nt < 4; ++nt) {
      st[nt] = __builtin_amdgcn_mfma_f32_16x16x32_bf16(
          ld_frag(sK + (nt * 16 + c) * LS + q4 * 8), bq0, st[nt], 0, 0, 0);
      st[nt] = __builtin_amdgcn_mfma_f32_16x16x32_bf16(
          ld_frag(sK + (nt * 16 + c) * LS + 32 + q4 * 8), bq1, st[nt], 0, 0, 0);
    }

    // softmax numerators + P write (rows wave-private; no barrier needed)
    const bool diag = (jt == it);
    u16* prow = sP + il * LS;
#pragma unroll
    for (int nt = 0; nt < 4; ++nt) {
      float e0 = __builtin_amdgcn_exp2f(st[nt][0]);
      float e1 = __builtin_amdgcn_exp2f(st[nt][1]);
      float e2 = __builtin_amdgcn_exp2f(st[nt][2]);
      float e3 = __builtin_amdgcn_exp2f(st[nt][3]);
      if (diag) {  // mask j > i: j = nt*16+q4*4+rg, i = il = w*16+c
        const int jb = nt * 16 + q4 * 4;
        e0 = (jb + 0 > il) ? 0.f : e0;
        e1 = (jb + 1 > il) ? 0.f : e1;
        e2 = (jb + 2 > il) ? 0.f : e2;
        e3 = (jb + 3 > il) ? 0.f : e3;
      }
      lsum += (e0 + e1) + (e2 + e3);
      uint2 pk = {pack_bf2(e0, e1), pack_bf2(e2, e3)};
      *(uint2*)&prow[nt * 16 + q4 * 4] = pk;
    }

    // O^T += V^T @ P^T: A = V^T-frag (sV row d), B = P-frag (sP row i=il)
    bf16x8 bp0 = ld_frag(sP + il * LS + q4 * 8);
    bf16x8 bp1 = ld_frag(sP + il * LS + 32 + q4 * 8);
#pragma unroll
    for (int dt = 0; dt < 4; ++dt) {
      oacc[dt] = __builtin_amdgcn_mfma_f32_16x16x32_bf16(
          ld_frag(sV + (dt * 16 + c) * LS + q4 * 8), bp0, oacc[dt], 0, 0, 0);
      oacc[dt] = __builtin_amdgcn_mfma_f32_16x16x32_bf16(
          ld_frag(sV + (dt * 16 + c) * LS + 32 + q4 * 8), bp1, oacc[dt], 0, 0, 0);
    }
  }

  // full row sum for i = il: reduce across the 4 q4-groups (lanes c, c+16, c+32, c+48)
  lsum += __shfl_xor(lsum, 16);
  lsum += __shfl_xor(lsum, 32);
  const float linv = 1.f / lsum;

  // write out[b, t=it*64+il, h*64 + dt*16+q4*4+rg] bf16, packed b64 stores
  const int b_ = bh >> 4, h_ = bh & 15;
  const int t_ = it * 64 + il;
  u16* orow = outp + ((size_t)(b_ * 1024 + t_)) * 1024 + h_ * 64;
#pragma unroll
  for (int dt = 0; dt < 4; ++dt) {
    uint2 ok = {pack_bf2(oacc[dt][0] * linv, oacc[dt][1] * linv),
                pack_bf2(oacc[dt][2] * linv, oacc[dt][3] * linv)};
    *(uint2*)&orow[dt * 16 + q4 * 4] = ok;
  }
}

// ---------------------------------------------------------------------------
// Launch
// ---------------------------------------------------------------------------
extern "C" void kernel_launch(void* const* d_in, const int* in_sizes, int n_in,
                              void* d_out, int out_size, void* d_ws, size_t ws_size,
                              hipStream_t stream) {
  const float* x       = (const float*)d_in[0];
  const float* ln1_g   = (const float*)d_in[1];
  const float* ln1_b   = (const float*)d_in[2];
  const float* attn_w  = (const float*)d_in[3];
  const float* attn_b  = (const float*)d_in[4];
  const float* attn_pw = (const float*)d_in[5];
  const float* attn_pb = (const float*)d_in[6];
  const float* ln2_g   = (const float*)d_in[7];
  const float* ln2_b   = (const float*)d_in[8];
  const float* fc_w    = (const float*)d_in[9];
  const float* fc_b    = (const float*)d_in[10];
  const float* mlp_w   = (const float*)d_in[11];
  const float* mlp_b   = (const float*)d_in[12];
  float* out = (float*)d_out;

  // workspace layout (bf16 elements)
  u16* ws = (u16*)d_ws;
  u16* mlpT     = ws;                         // 1024*4096
  u16* attn_wT  = mlpT + 1024 * 4096;         // 3072*1024
  u16* attn_pwT = attn_wT + 3072 * 1024;      // 1024*1024
  u16* fcT      = attn_pwT + 1024 * 1024;     // 4096*1024
  u16* hbuf     = fcT + 4096 * 1024;          // 8192*1024
  u16* kqv      = hbuf + 8192 * 1024;         // 8192*3072 (per-head layout)
  u16* attn_o   = kqv + (size_t)8192 * 3072;  // 8192*1024
  u16* mbuf     = kqv;                        // 8192*4096 (reuses kqv+attn_o)

  dim3 tb(32, 8);
  transpose_bf16<<<dim3(96, 32),  tb, 0, stream>>>(attn_w,  attn_wT,  1024, 3072);
  transpose_bf16<<<dim3(32, 32),  tb, 0, stream>>>(attn_pw, attn_pwT, 1024, 1024);
  transpose_bf16<<<dim3(128, 32), tb, 0, stream>>>(fc_w,    fcT,      1024, 4096);
  transpose_bf16<<<dim3(32, 128), tb, 0, stream>>>(mlp_w,   mlpT,     4096, 1024);

  ln_kernel<<<8192, 256, 0, stream>>>(x, ln1_g, ln1_b, hbuf);

  gemm_kqv<<<dim3(24, 64), 256, 0, stream>>>(hbuf, attn_wT, attn_b, kqv, 8192, 3072, 1024);

  attn_kernel<<<dim3(128, 16), 256, 0, stream>>>(kqv, attn_o);

  gemm_resid<<<dim3(8, 32), 512, 0, stream>>>(attn_o, attn_pwT, attn_pb, out, x,
                                              8192, 1024, 1024);

  ln_kernel<<<8192, 256, 0, stream>>>(out, ln2_g, ln2_b, hbuf);

  gemm_gelu<<<dim3(32, 32), 512, 0, stream>>>(hbuf, fcT, fc_b, mbuf, 8192, 4096, 1024);

  gemm_add<<<dim3(8, 32), 512, 0, stream>>>(mbuf, mlpT, mlp_b, out, 8192, 1024, 4096);
}

// Round 8
// 451.124 us; speedup vs baseline: 1.0375x; 1.0375x over previous
//
#include <hip/hip_runtime.h>
#include <stdint.h>

typedef unsigned short u16;
typedef __bf16 bf16x8 __attribute__((ext_vector_type(8)));
typedef float f32x4 __attribute__((ext_vector_type(4)));

#define DEVINL static __device__ __forceinline__

// fp32 -> bf16 round-to-nearest-even
DEVINL u16 f2bf(float f) {
  uint32_t u = __builtin_bit_cast(uint32_t, f);
  u += 0x7fffu + ((u >> 16) & 1u);
  return (u16)(u >> 16);
}

// pack two fp32 -> bf16x2 dword (round-half-up: +0x8000 then take hi16)
DEVINL uint32_t pack_bf2(float f0, float f1) {
  uint32_t u0 = __builtin_bit_cast(uint32_t, f0) + 0x8000u;
  uint32_t u1 = __builtin_bit_cast(uint32_t, f1) + 0x8000u;
  return __builtin_amdgcn_perm(u1, u0, 0x07060302u);  // [u1.hi16, u0.hi16]
}

DEVINL bf16x8 ld_frag(const u16* p) { return *(const bf16x8*)p; }

DEVINL void gld_lds16(const void* g, void* l) {
  __builtin_amdgcn_global_load_lds((const __attribute__((address_space(1))) void*)g,
                                   (__attribute__((address_space(3))) void*)l, 16, 0, 0);
}

DEVINL int swz4(int r) { return (r & 3) ^ ((r >> 2) & 3); }

// T1: bijective XCD-chunked swizzle, 128-row tiles (body2 grids, nwg % 8 == 0).
DEVINL void xcd_tile(int& tm, int& tn) {
  const int gx = gridDim.x;
  const int flat = blockIdx.x + gx * blockIdx.y;
  const int q = (gx * gridDim.y) >> 3;
  const int wg = (flat & 7) * q + (flat >> 3);
  tn = (wg % gx) * 128;
  tm = (wg / gx) * 128;
}

// T1 for 256-row tiles (bodyW grids).
DEVINL void xcd_tile_wide(int& tm, int& tn) {
  const int gx = gridDim.x;
  const int flat = blockIdx.x + gx * blockIdx.y;
  const int q = (gx * gridDim.y) >> 3;
  const int wg = (flat & 7) * q + (flat >> 3);
  tn = (wg % gx) * 128;
  tm = (wg / gx) * 256;
}

// ---------------------------------------------------------------------------
// Weight convert+transpose: W fp32 (K,N) row-major -> Wt bf16 (N,K) row-major
// ---------------------------------------------------------------------------
__global__ __launch_bounds__(256)
void transpose_bf16(const float* __restrict__ W, u16* __restrict__ Wt, int K, int N) {
  __shared__ float tile[32][33];
  const int n0 = blockIdx.x * 32, k0 = blockIdx.y * 32;
  const int tx = threadIdx.x, ty = threadIdx.y;  // (32,8)
#pragma unroll
  for (int i = 0; i < 32; i += 8)
    tile[ty + i][tx] = W[(size_t)(k0 + ty + i) * N + n0 + tx];
  __syncthreads();
#pragma unroll
  for (int i = 0; i < 32; i += 8)
    Wt[(size_t)(n0 + ty + i) * K + k0 + tx] = f2bf(tile[tx][ty + i]);
}

// ---------------------------------------------------------------------------
// LayerNorm: fp32 (rows,1024) -> bf16, single pass (E[x^2]-mu^2), eps=1e-5
// ---------------------------------------------------------------------------
__global__ __launch_bounds__(256)
void ln_kernel(const float* __restrict__ x, const float* __restrict__ g,
               const float* __restrict__ b, u16* __restrict__ out) {
  __shared__ float red[8];
  const size_t row = blockIdx.x;
  const int tid = threadIdx.x;
  float4 v = ((const float4*)(x + row * 1024))[tid];
  float s = v.x + v.y + v.z + v.w;
  float s2 = v.x * v.x + v.y * v.y + v.z * v.z + v.w * v.w;
#pragma unroll
  for (int o = 32; o; o >>= 1) { s += __shfl_down(s, o); s2 += __shfl_down(s2, o); }
  const int w = tid >> 6;
  if ((tid & 63) == 0) { red[w * 2] = s; red[w * 2 + 1] = s2; }
  __syncthreads();
  const float S = red[0] + red[2] + red[4] + red[6];
  const float S2 = red[1] + red[3] + red[5] + red[7];
  const float mu = S * (1.f / 1024.f);
  const float var = S2 * (1.f / 1024.f) - mu * mu;
  const float rstd = rsqrtf(var + 1e-5f);
  float4 gv = ((const float4*)g)[tid];
  float4 bv = ((const float4*)b)[tid];
  ushort4 o;
  o.x = f2bf((v.x - mu) * rstd * gv.x + bv.x);
  o.y = f2bf((v.y - mu) * rstd * gv.y + bv.y);
  o.z = f2bf((v.z - mu) * rstd * gv.z + bv.z);
  o.w = f2bf((v.w - mu) * rstd * gv.w + bv.w);
  ((ushort4*)(out + row * 1024))[tid] = o;
}

// ---------------------------------------------------------------------------
// Shared epilogue: C row/col scatter with fused ops.
// ---------------------------------------------------------------------------
enum { EPI_KQV = 0, EPI_RESID = 1, EPI_GELU = 2, EPI_ADD = 3 };

template <int EPI>
DEVINL void gemm_epilogue(f32x4 (&acc)[4][4], const float* __restrict__ bias,
                          void* __restrict__ outp, const float* __restrict__ resid,
                          int N, int tm, int tn, int mh, int nh, int q4, int c) {
#pragma unroll
  for (int mt = 0; mt < 4; ++mt) {
#pragma unroll
    for (int nt = 0; nt < 4; ++nt) {
      const int col = tn + nh + nt * 16 + c;
      const float bcol = bias[col];
#pragma unroll
      for (int rg = 0; rg < 4; ++rg) {
        const int row = tm + mh + mt * 16 + q4 * 4 + rg;
        float val = acc[mt][nt][rg] + bcol;
        if constexpr (EPI == EPI_KQV) {
          // scatter to per-head layout [b,h][s][...]; s: 0=k (flash-Q, pre-scaled
          // by 0.125*log2e for exp2-domain softmax), 1=q (t,d), 2=v stored (d,t)
          const int bb = row >> 10, t = row & 1023;
          const int s = col >> 10, rem = col & 1023;
          const int hh = rem >> 6, d = rem & 63;
          if (s == 0) val *= 0.18033688011112042f;  // 0.125 * log2(e)
          const size_t base = ((size_t)((bb * 16 + hh) * 3 + s)) << 16;
          const size_t idx = (s == 2) ? base + (size_t)d * 1024 + t : base + (size_t)t * 64 + d;
          ((u16*)outp)[idx] = f2bf(val);
        } else if constexpr (EPI == EPI_RESID) {
          const size_t idx = (size_t)row * 1024 + col;
          ((float*)outp)[idx] = val + resid[idx];
        } else if constexpr (EPI == EPI_GELU) {
          // tanh-approx GELU via single exp2: x*sigmoid(1.5957691(x+0.044715x^3))
          const float x2 = val * val;
          const float t = __builtin_fmaf(x2, -0.102952445f, -2.30221235f);  // *log2e folded
          const float e = __builtin_amdgcn_exp2f(val * t);
          const float ge = val * __builtin_amdgcn_rcpf(1.0f + e);
          ((u16*)outp)[(size_t)row * N + col] = f2bf(ge);
        } else {  // EPI_ADD: accumulate into fp32 out (sole writer)
          const size_t idx = (size_t)row * 1024 + col;
          ((float*)outp)[idx] += val;
        }
      }
    }
  }
}

// ---------------------------------------------------------------------------
// GEMM body2 (128x128, 4 waves, 2-buffer): for grids with >=4 blocks/CU of
// TLP (kqv). Round-4/7-verified; beats bodyW on the 1536-block kqv shape.
// ---------------------------------------------------------------------------
template <int EPI>
DEVINL void gemm_body2(const u16* __restrict__ A, const u16* __restrict__ Bt,
                       const float* __restrict__ bias, void* __restrict__ outp,
                       const float* __restrict__ resid, int M, int N, int K,
                       int tm, int tn) {
  __shared__ alignas(16) u16 sA[2][128 * 32];
  __shared__ alignas(16) u16 sB[2][128 * 32];
  const int tid = threadIdx.x;
  const int w = tid >> 6, l = tid & 63;
  const int q4 = l >> 4, c = l & 15;
  const int mh = (w >> 1) * 64, nh = (w & 1) * 64;
  const int cg8 = (q4 ^ swz4(c)) * 8;

  f32x4 acc[4][4] = {};

  const int srow = l >> 2;
  const int scol = ((l & 3) ^ swz4(srow)) * 8;
  const u16* gA0 = A + (size_t)(tm + (w * 2) * 16 + srow) * K + scol;
  const u16* gA1 = A + (size_t)(tm + (w * 2 + 1) * 16 + srow) * K + scol;
  const u16* gB0 = Bt + (size_t)(tn + (w * 2) * 16 + srow) * K + scol;
  const u16* gB1 = Bt + (size_t)(tn + (w * 2 + 1) * 16 + srow) * K + scol;
  const int cA0 = (w * 2) * 512, cA1 = (w * 2 + 1) * 512;

  const int nIters = K / 32;
#define STAGE2(buf, k0)                         \
  do {                                          \
    gld_lds16(gA0 + (k0), &sA[buf][cA0]);       \
    gld_lds16(gA1 + (k0), &sA[buf][cA1]);       \
    gld_lds16(gB0 + (k0), &sB[buf][cA0]);       \
    gld_lds16(gB1 + (k0), &sB[buf][cA1]);       \
  } while (0)

  STAGE2(0, 0);
  for (int i = 0; i < nIters; ++i) {
    const int cur = i & 1;
    asm volatile("s_waitcnt vmcnt(0)" ::: "memory");  // buf[cur] staged
    __syncthreads();  // all waves done reading buf[cur^1] (iter i-1) + see stage
    if (i + 1 < nIters) STAGE2(cur ^ 1, (i + 1) * 32);  // overlaps compute below
    const u16* bA = sA[cur];
    const u16* bB = sB[cur];
    bf16x8 af[4], bfv[4];
#pragma unroll
    for (int mt = 0; mt < 4; ++mt) af[mt] = ld_frag(bA + (mh + mt * 16 + c) * 32 + cg8);
#pragma unroll
    for (int nt = 0; nt < 4; ++nt) bfv[nt] = ld_frag(bB + (nh + nt * 16 + c) * 32 + cg8);
#pragma unroll
    for (int mt = 0; mt < 4; ++mt)
#pragma unroll
      for (int nt = 0; nt < 4; ++nt)
        acc[mt][nt] = __builtin_amdgcn_mfma_f32_16x16x32_bf16(af[mt], bfv[nt], acc[mt][nt], 0, 0, 0);
  }
#undef STAGE2
  gemm_epilogue<EPI>(acc, bias, outp, resid, N, tm, tn, mh, nh, q4, c);
}

// ---------------------------------------------------------------------------
// GEMM body WIDE (256x128 tile, 8 waves, BK=64, 3-deep ring, 144KB LDS).
// Round-5 loop (best known): counted vmcnt(6), single barrier-pair per K-step,
// conflicts=0 (row-XOR swizzle both-sides). Requires K/64 >= 3, nwg % 8 == 0.
// Best at <=2 block-rounds/CU (gelu/resid/add); loses to body2 at high TLP.
// ---------------------------------------------------------------------------
template <int EPI>
DEVINL void gemm_bodyW(const u16* __restrict__ A, const u16* __restrict__ Bt,
                       const float* __restrict__ bias, void* __restrict__ outp,
                       const float* __restrict__ resid, int N, int K,
                       int tm, int tn) {
  __shared__ alignas(16) u16 sT[3][48 * 512];
  const int tid = threadIdx.x;
  const int w = tid >> 6, l = tid & 63;
  const int q4 = l >> 4, c = l & 15;
  const int mh = (w >> 1) * 64, nh = (w & 1) * 64;  // 4M x 2N waves of 64x64

  f32x4 acc[4][4] = {};

  const int lr = l >> 3;
  const int lc = ((l & 7) ^ lr) * 8;  // pre-swizzled global k-offset (elems)
  const u16* gA[4];
  const u16* gB[2];
#pragma unroll
  for (int j = 0; j < 4; ++j) gA[j] = A + (size_t)(tm + 32 * w + j * 8 + lr) * K + lc;
#pragma unroll
  for (int j = 0; j < 2; ++j) gB[j] = Bt + (size_t)(tn + 16 * w + j * 8 + lr) * K + lc;

  auto stageW = [&](int buf, int k0) {
#pragma unroll
    for (int j = 0; j < 4; ++j) gld_lds16(gA[j] + k0, &sT[buf][(4 * w + j) * 512]);
#pragma unroll
    for (int j = 0; j < 2; ++j) gld_lds16(gB[j] + k0, &sT[buf][(32 + 2 * w + j) * 512]);
  };

  auto computeW = [&](int cur) {
    const u16* bufA = sT[cur];
    const u16* bufB = sT[cur] + 32 * 512;
#pragma unroll
    for (int kh = 0; kh < 2; ++kh) {
      bf16x8 af[4], bfv[4];
#pragma unroll
      for (int mt = 0; mt < 4; ++mt) {
        const int row = mh + mt * 16 + c;
        af[mt] = ld_frag(bufA + row * 64 + ((kh * 4 + q4) ^ (c & 7)) * 8);
      }
#pragma unroll
      for (int nt = 0; nt < 4; ++nt) {
        const int row = nh + nt * 16 + c;
        bfv[nt] = ld_frag(bufB + row * 64 + ((kh * 4 + q4) ^ (c & 7)) * 8);
      }
      __builtin_amdgcn_s_setprio(1);
#pragma unroll
      for (int mt = 0; mt < 4; ++mt)
#pragma unroll
        for (int nt = 0; nt < 4; ++nt)
          acc[mt][nt] = __builtin_amdgcn_mfma_f32_16x16x32_bf16(af[mt], bfv[nt], acc[mt][nt], 0, 0, 0);
      __builtin_amdgcn_s_setprio(0);
    }
  };

  const int nI = K / 64;  // >= 3 required
  stageW(0, 0);
  stageW(1, 64);
  int bc = 0;  // buffer being computed; stage target = (bc+2)%3
  int i = 0;
  for (; i < nI - 1; ++i) {
    asm volatile("s_waitcnt vmcnt(6)" ::: "memory");
    __builtin_amdgcn_s_barrier();
    asm volatile("" ::: "memory");
    if (i + 2 < nI) {
      const int tgt = (bc >= 1) ? bc - 1 : 2;  // (bc+2)%3
      stageW(tgt, (i + 2) * 64);
    }
    computeW(bc);
    bc = (bc < 2) ? bc + 1 : 0;
  }
  asm volatile("s_waitcnt vmcnt(0)" ::: "memory");
  __builtin_amdgcn_s_barrier();
  asm volatile("" ::: "memory");
  computeW(bc);

  gemm_epilogue<EPI>(acc, bias, outp, resid, N, tm, tn, mh, nh, q4, c);
}

// ---- wrappers (distinct names so rocprof attributes per GEMM instance) ----
__global__ __launch_bounds__(256)
void gemm_kqv(const u16* __restrict__ A, const u16* __restrict__ Bt,
              const float* __restrict__ bias, u16* __restrict__ outp,
              int M, int N, int K) {
  int tm, tn;
  xcd_tile(tm, tn);
  gemm_body2<EPI_KQV>(A, Bt, bias, outp, nullptr, M, N, K, tm, tn);
}

__global__ __launch_bounds__(512)
void gemm_gelu(const u16* __restrict__ A, const u16* __restrict__ Bt,
               const float* __restrict__ bias, u16* __restrict__ outp,
               int M, int N, int K) {
  int tm, tn;
  xcd_tile_wide(tm, tn);
  gemm_bodyW<EPI_GELU>(A, Bt, bias, outp, nullptr, N, K, tm, tn);
}

__global__ __launch_bounds__(512)
void gemm_resid(const u16* __restrict__ A, const u16* __restrict__ Bt,
                const float* __restrict__ bias, float* __restrict__ outp,
                const float* __restrict__ resid, int M, int N, int K) {
  int tm, tn;
  xcd_tile_wide(tm, tn);
  gemm_bodyW<EPI_RESID>(A, Bt, bias, outp, resid, N, K, tm, tn);
}

__global__ __launch_bounds__(512)
void gemm_add(const u16* __restrict__ A, const u16* __restrict__ Bt,
              const float* __restrict__ bias, float* __restrict__ outp,
              int M, int N, int K) {
  int tm, tn;
  xcd_tile_wide(tm, tn);
  gemm_bodyW<EPI_ADD>(A, Bt, bias, outp, nullptr, N, K, tm, tn);
}

// ---------------------------------------------------------------------------
// Flash attention, causal, fixed-max softmax in exp2 domain — 128-row Q-tiles.
// 512 threads = 8 waves; wave w owns i-rows il = w*16+c (il in 0..127), so all
// per-lane compute logic is identical to the verified 64-row kernel. K/V tiles
// (KVBLK=64) staged once per 128 Q-rows instead of 64 -> staging and redundant
// global K/V re-reads drop ~2x (136 -> 72 tile-stages per bh).
// Causal mask threshold generalizes: thr = il + it*128 - jt*64 (>=64 means no
// mask; only the last two jt tiles can mask). Waves entirely above the
// diagonal skip compute (wave-uniform guard; barriers still executed).
// Staging is the r5 serial pattern (NO T14 reg-prefetch — r7 showed it hurts).
// ---------------------------------------------------------------------------
__global__ __launch_bounds__(512)
void attn_kernel(const u16* __restrict__ kqv, u16* __restrict__ outp) {
  constexpr int LS = 72;  // padded stride: 144B rows, 16B aligned, 2-way max conflicts
  __shared__ alignas(16) u16 sP[128 * LS];  // Q tile at start, then P (aliased)
  __shared__ alignas(16) u16 sK[64 * LS];
  __shared__ alignas(16) u16 sV[64 * LS];   // V^T tile: row=d, col=j
  const int bh = blockIdx.x;
  const int it = (int)gridDim.y - 1 - (int)blockIdx.y;  // longest blocks dispatch first
  const int tid = threadIdx.x;
  const int w = tid >> 6, l = tid & 63, q4 = l >> 4, c = l & 15;
  const int il = w * 16 + c;  // this lane's i-row within the 128-row tile
  const size_t hb = (size_t)bh * 3 * 65536;
  const u16* qbase = kqv + hb;               // flash-Q (T,D), pre-scaled
  const u16* kbase = kqv + hb + 65536;       // flash-K (T,D)
  const u16* vbase = kqv + hb + 2 * 65536;   // V^T (D,T)

  // stage 128-row Q tile into sP (aliased; consumed once after first barrier)
  const int sr = tid >> 3, sc = (tid & 7) * 8;   // 512 threads: rows 0..63 (+64)
  *(int4*)&sP[sr * LS + sc] = *(const int4*)(qbase + (size_t)(it * 128 + sr) * 64 + sc);
  *(int4*)&sP[(sr + 64) * LS + sc] =
      *(const int4*)(qbase + (size_t)(it * 128 + sr + 64) * 64 + sc);

  f32x4 oacc[4] = {};   // O^T: oacc[dt][rg] = O[i=il][d=dt*16+q4*4+rg]
  float lsum = 0.f;     // per-lane partial row-sum for row i=il
  bf16x8 bq0, bq1;      // loop-invariant Q B-frags (lane's own row)

  const int jtMax = 2 * it + 1;
  for (int jt = 0; jt <= jtMax; ++jt) {
    if (jt) __syncthreads();  // prior iter's sK/sV reads done before overwrite
    *(int4*)&sK[sr * LS + sc] = *(const int4*)(kbase + (size_t)(jt * 64 + sr) * 64 + sc);
    *(int4*)&sV[sr * LS + sc] = *(const int4*)(vbase + (size_t)sr * 1024 + jt * 64 + sc);
    __syncthreads();
    if (jt == 0) {  // Q frags: B[k=d][n=i]: lane reads fQ[i=il][d=q4*8..]
      bq0 = ld_frag(sP + il * LS + q4 * 8);
      bq1 = ld_frag(sP + il * LS + 32 + q4 * 8);
    }

    // wave-uniform skip: all 16 rows of this wave above the diagonal
    if (jt * 64 > it * 128 + w * 16 + 15) continue;

    // S^T = fK @ fQ^T: st[nt] row j=nt*16+q4*4+rg, col i=il (log2 domain)
    f32x4 st[4] = {};
#pragma unroll
    for (int nt = 0; nt < 4; ++nt) {
      st[nt] = __builtin_amdgcn_mfma_f32_16x16x32_bf16(
          ld_frag(sK + (nt * 16 + c) * LS + q4 * 8), bq0, st[nt], 0, 0, 0);
      st[nt] = __builtin_amdgcn_mfma_f32_16x16x32_bf16(
          ld_frag(sK + (nt * 16 + c) * LS + 32 + q4 * 8), bq1, st[nt], 0, 0, 0);
    }

    // softmax numerators + P write (rows wave-private; no barrier needed)
    const bool diag = (jt >= 2 * it);             // only last two tiles can mask
    const int thr = il + it * 128 - jt * 64;      // mask j-local > thr
    u16* prow = sP + il * LS;
#pragma unroll
    for (int nt = 0; nt < 4; ++nt) {
      float e0 = __builtin_amdgcn_exp2f(st[nt][0]);
      float e1 = __builtin_amdgcn_exp2f(st[nt][1]);
      float e2 = __builtin_amdgcn_exp2f(st[nt][2]);
      float e3 = __builtin_amdgcn_exp2f(st[nt][3]);
      if (diag) {  // mask j > i: j-local = nt*16+q4*4+rg
        const int jb = nt * 16 + q4 * 4;
        e0 = (jb + 0 > thr) ? 0.f : e0;
        e1 = (jb + 1 > thr) ? 0.f : e1;
        e2 = (jb + 2 > thr) ? 0.f : e2;
        e3 = (jb + 3 > thr) ? 0.f : e3;
      }
      lsum += (e0 + e1) + (e2 + e3);
      uint2 pk = {pack_bf2(e0, e1), pack_bf2(e2, e3)};
      *(uint2*)&prow[nt * 16 + q4 * 4] = pk;
    }

    // O^T += V^T @ P^T: A = V^T-frag (sV row d), B = P-frag (sP row i=il)
    bf16x8 bp0 = ld_frag(sP + il * LS + q4 * 8);
    bf16x8 bp1 = ld_frag(sP + il * LS + 32 + q4 * 8);
#pragma unroll
    for (int dt = 0; dt < 4; ++dt) {
      oacc[dt] = __builtin_amdgcn_mfma_f32_16x16x32_bf16(
          ld_frag(sV + (dt * 16 + c) * LS + q4 * 8), bp0, oacc[dt], 0, 0, 0);
      oacc[dt] = __builtin_amdgcn_mfma_f32_16x16x32_bf16(
          ld_frag(sV + (dt * 16 + c) * LS + 32 + q4 * 8), bp1, oacc[dt], 0, 0, 0);
    }
  }

  // full row sum for i = il: reduce across the 4 q4-groups (lanes c, c+16, c+32, c+48)
  lsum += __shfl_xor(lsum, 16);
  lsum += __shfl_xor(lsum, 32);
  const float linv = 1.f / lsum;

  // write out[b, t=it*128+il, h*64 + dt*16+q4*4+rg] bf16, packed b64 stores
  const int b_ = bh >> 4, h_ = bh & 15;
  const int t_ = it * 128 + il;
  u16* orow = outp + ((size_t)(b_ * 1024 + t_)) * 1024 + h_ * 64;
#pragma unroll
  for (int dt = 0; dt < 4; ++dt) {
    uint2 ok = {pack_bf2(oacc[dt][0] * linv, oacc[dt][1] * linv),
                pack_bf2(oacc[dt][2] * linv, oacc[dt][3] * linv)};
    *(uint2*)&orow[dt * 16 + q4 * 4] = ok;
  }
}

// ---------------------------------------------------------------------------
// Launch
// ---------------------------------------------------------------------------
extern "C" void kernel_launch(void* const* d_in, const int* in_sizes, int n_in,
                              void* d_out, int out_size, void* d_ws, size_t ws_size,
                              hipStream_t stream) {
  const float* x       = (const float*)d_in[0];
  const float* ln1_g   = (const float*)d_in[1];
  const float* ln1_b   = (const float*)d_in[2];
  const float* attn_w  = (const float*)d_in[3];
  const float* attn_b  = (const float*)d_in[4];
  const float* attn_pw = (const float*)d_in[5];
  const float* attn_pb = (const float*)d_in[6];
  const float* ln2_g   = (const float*)d_in[7];
  const float* ln2_b   = (const float*)d_in[8];
  const float* fc_w    = (const float*)d_in[9];
  const float* fc_b    = (const float*)d_in[10];
  const float* mlp_w   = (const float*)d_in[11];
  const float* mlp_b   = (const float*)d_in[12];
  float* out = (float*)d_out;

  // workspace layout (bf16 elements)
  u16* ws = (u16*)d_ws;
  u16* mlpT     = ws;                         // 1024*4096
  u16* attn_wT  = mlpT + 1024 * 4096;         // 3072*1024
  u16* attn_pwT = attn_wT + 3072 * 1024;      // 1024*1024
  u16* fcT      = attn_pwT + 1024 * 1024;     // 4096*1024
  u16* hbuf     = fcT + 4096 * 1024;          // 8192*1024
  u16* kqv      = hbuf + 8192 * 1024;         // 8192*3072 (per-head layout)
  u16* attn_o   = kqv + (size_t)8192 * 3072;  // 8192*1024
  u16* mbuf     = kqv;                        // 8192*4096 (reuses kqv+attn_o)

  dim3 tb(32, 8);
  transpose_bf16<<<dim3(96, 32),  tb, 0, stream>>>(attn_w,  attn_wT,  1024, 3072);
  transpose_bf16<<<dim3(32, 32),  tb, 0, stream>>>(attn_pw, attn_pwT, 1024, 1024);
  transpose_bf16<<<dim3(128, 32), tb, 0, stream>>>(fc_w,    fcT,      1024, 4096);
  transpose_bf16<<<dim3(32, 128), tb, 0, stream>>>(mlp_w,   mlpT,     4096, 1024);

  ln_kernel<<<8192, 256, 0, stream>>>(x, ln1_g, ln1_b, hbuf);

  gemm_kqv<<<dim3(24, 64), 256, 0, stream>>>(hbuf, attn_wT, attn_b, kqv, 8192, 3072, 1024);

  attn_kernel<<<dim3(128, 8), 512, 0, stream>>>(kqv, attn_o);

  gemm_resid<<<dim3(8, 32), 512, 0, stream>>>(attn_o, attn_pwT, attn_pb, out, x,
                                              8192, 1024, 1024);

  ln_kernel<<<8192, 256, 0, stream>>>(out, ln2_g, ln2_b, hbuf);

  gemm_gelu<<<dim3(32, 32), 512, 0, stream>>>(hbuf, fcT, fc_b, mbuf, 8192, 4096, 1024);

  gemm_add<<<dim3(8, 32), 512, 0, stream>>>(mbuf, mlpT, mlp_b, out, 8192, 1024, 4096);
}

// Round 10
// 432.585 us; speedup vs baseline: 1.0820x; 1.0429x over previous
//
#include <hip/hip_runtime.h>
#include <stdint.h>

typedef unsigned short u16;
typedef __bf16 bf16x8 __attribute__((ext_vector_type(8)));
typedef float f32x4 __attribute__((ext_vector_type(4)));

#define DEVINL static __device__ __forceinline__

// fp32 -> bf16 round-to-nearest-even
DEVINL u16 f2bf(float f) {
  uint32_t u = __builtin_bit_cast(uint32_t, f);
  u += 0x7fffu + ((u >> 16) & 1u);
  return (u16)(u >> 16);
}

// pack two fp32 -> bf16x2 dword (round-half-up: +0x8000 then take hi16)
DEVINL uint32_t pack_bf2(float f0, float f1) {
  uint32_t u0 = __builtin_bit_cast(uint32_t, f0) + 0x8000u;
  uint32_t u1 = __builtin_bit_cast(uint32_t, f1) + 0x8000u;
  return __builtin_amdgcn_perm(u1, u0, 0x07060302u);  // [u1.hi16, u0.hi16]
}

DEVINL bf16x8 ld_frag(const u16* p) { return *(const bf16x8*)p; }

DEVINL void gld_lds16(const void* g, void* l) {
  __builtin_amdgcn_global_load_lds((const __attribute__((address_space(1))) void*)g,
                                   (__attribute__((address_space(3))) void*)l, 16, 0, 0);
}

DEVINL int swz4(int r) { return (r & 3) ^ ((r >> 2) & 3); }

// T1: bijective XCD-chunked swizzle, 128-row tiles (body2 grids, nwg % 8 == 0).
DEVINL void xcd_tile(int& tm, int& tn) {
  const int gx = gridDim.x;
  const int flat = blockIdx.x + gx * blockIdx.y;
  const int q = (gx * gridDim.y) >> 3;
  const int wg = (flat & 7) * q + (flat >> 3);
  tn = (wg % gx) * 128;
  tm = (wg / gx) * 128;
}

// T1 for 256-row tiles (bodyW grids).
DEVINL void xcd_tile_wide(int& tm, int& tn) {
  const int gx = gridDim.x;
  const int flat = blockIdx.x + gx * blockIdx.y;
  const int q = (gx * gridDim.y) >> 3;
  const int wg = (flat & 7) * q + (flat >> 3);
  tn = (wg % gx) * 128;
  tm = (wg / gx) * 256;
}

// ---------------------------------------------------------------------------
// Weight convert+transpose: W fp32 (K,N) row-major -> Wt bf16 (N,K) row-major
// ---------------------------------------------------------------------------
__global__ __launch_bounds__(256)
void transpose_bf16(const float* __restrict__ W, u16* __restrict__ Wt, int K, int N) {
  __shared__ float tile[32][33];
  const int n0 = blockIdx.x * 32, k0 = blockIdx.y * 32;
  const int tx = threadIdx.x, ty = threadIdx.y;  // (32,8)
#pragma unroll
  for (int i = 0; i < 32; i += 8)
    tile[ty + i][tx] = W[(size_t)(k0 + ty + i) * N + n0 + tx];
  __syncthreads();
#pragma unroll
  for (int i = 0; i < 32; i += 8)
    Wt[(size_t)(n0 + ty + i) * K + k0 + tx] = f2bf(tile[tx][ty + i]);
}

// ---------------------------------------------------------------------------
// LayerNorm: fp32 (rows,1024) -> bf16, single pass (E[x^2]-mu^2), eps=1e-5
// ---------------------------------------------------------------------------
__global__ __launch_bounds__(256)
void ln_kernel(const float* __restrict__ x, const float* __restrict__ g,
               const float* __restrict__ b, u16* __restrict__ out) {
  __shared__ float red[8];
  const size_t row = blockIdx.x;
  const int tid = threadIdx.x;
  float4 v = ((const float4*)(x + row * 1024))[tid];
  float s = v.x + v.y + v.z + v.w;
  float s2 = v.x * v.x + v.y * v.y + v.z * v.z + v.w * v.w;
#pragma unroll
  for (int o = 32; o; o >>= 1) { s += __shfl_down(s, o); s2 += __shfl_down(s2, o); }
  const int w = tid >> 6;
  if ((tid & 63) == 0) { red[w * 2] = s; red[w * 2 + 1] = s2; }
  __syncthreads();
  const float S = red[0] + red[2] + red[4] + red[6];
  const float S2 = red[1] + red[3] + red[5] + red[7];
  const float mu = S * (1.f / 1024.f);
  const float var = S2 * (1.f / 1024.f) - mu * mu;
  const float rstd = rsqrtf(var + 1e-5f);
  float4 gv = ((const float4*)g)[tid];
  float4 bv = ((const float4*)b)[tid];
  ushort4 o;
  o.x = f2bf((v.x - mu) * rstd * gv.x + bv.x);
  o.y = f2bf((v.y - mu) * rstd * gv.y + bv.y);
  o.z = f2bf((v.z - mu) * rstd * gv.z + bv.z);
  o.w = f2bf((v.w - mu) * rstd * gv.w + bv.w);
  ((ushort4*)(out + row * 1024))[tid] = o;
}

// ---------------------------------------------------------------------------
// Shared epilogue: C row/col scatter with fused ops (bodyW users).
// ---------------------------------------------------------------------------
enum { EPI_KQV = 0, EPI_RESID = 1, EPI_GELU = 2, EPI_ADD = 3 };

template <int EPI>
DEVINL void gemm_epilogue(f32x4 (&acc)[4][4], const float* __restrict__ bias,
                          void* __restrict__ outp, const float* __restrict__ resid,
                          int N, int tm, int tn, int mh, int nh, int q4, int c) {
#pragma unroll
  for (int mt = 0; mt < 4; ++mt) {
#pragma unroll
    for (int nt = 0; nt < 4; ++nt) {
      const int col = tn + nh + nt * 16 + c;
      const float bcol = bias[col];
#pragma unroll
      for (int rg = 0; rg < 4; ++rg) {
        const int row = tm + mh + mt * 16 + q4 * 4 + rg;
        float val = acc[mt][nt][rg] + bcol;
        if constexpr (EPI == EPI_RESID) {
          const size_t idx = (size_t)row * 1024 + col;
          ((float*)outp)[idx] = val + resid[idx];
        } else if constexpr (EPI == EPI_GELU) {
          // tanh-approx GELU via single exp2: x*sigmoid(1.5957691(x+0.044715x^3))
          const float x2 = val * val;
          const float t = __builtin_fmaf(x2, -0.102952445f, -2.30221235f);  // *log2e folded
          const float e = __builtin_amdgcn_exp2f(val * t);
          const float ge = val * __builtin_amdgcn_rcpf(1.0f + e);
          ((u16*)outp)[(size_t)row * N + col] = f2bf(ge);
        } else {  // EPI_ADD: accumulate into fp32 out (sole writer)
          const size_t idx = (size_t)row * 1024 + col;
          ((float*)outp)[idx] += val;
        }
      }
    }
  }
}

// ---------------------------------------------------------------------------
// GEMM body2 (128x128, 4 waves, 2-buffer) — KQV only.
// K-loop unchanged (r4/r7-verified). Epilogue specialized:
//  - s<2 (k,q) blocks: original (t,d)-layout scalar stores (32B runs).
//  - s==2 (v) blocks: (d,t)-layout was a 2KB-stride u16 scatter (16x write
//    transaction amplification). Fixed via LDS transpose: acc -> smem[128][136]
//    (uint2, t-consecutive), barrier, re-read row-wise -> coalesced 128B-run
//    global stores. Reuses the (dead) staging LDS, grown 32->34.8KB.
//  s = tn>>10 is block-uniform (tn multiple of 128, band = 1024 cols).
//  r9 bug fixed: read-back copy is 8 x int4 at stride 8 u16 (was 4 x int4 at
//  stride 16 u16 — skipped half of every V row).
// ---------------------------------------------------------------------------
template <int EPI>
DEVINL void gemm_body2(const u16* __restrict__ A, const u16* __restrict__ Bt,
                       const float* __restrict__ bias, void* __restrict__ outp,
                       const float* __restrict__ resid, int M, int N, int K,
                       int tm, int tn) {
  __shared__ alignas(16) u16 smem[17408];  // 34.8KB; K-loop uses first 32KB
  u16* sA = smem;          // [2][128*32]
  u16* sB = smem + 8192;   // [2][128*32]
  const int tid = threadIdx.x;
  const int w = tid >> 6, l = tid & 63;
  const int q4 = l >> 4, c = l & 15;
  const int mh = (w >> 1) * 64, nh = (w & 1) * 64;
  const int cg8 = (q4 ^ swz4(c)) * 8;

  f32x4 acc[4][4] = {};

  const int srow = l >> 2;
  const int scol = ((l & 3) ^ swz4(srow)) * 8;
  const u16* gA0 = A + (size_t)(tm + (w * 2) * 16 + srow) * K + scol;
  const u16* gA1 = A + (size_t)(tm + (w * 2 + 1) * 16 + srow) * K + scol;
  const u16* gB0 = Bt + (size_t)(tn + (w * 2) * 16 + srow) * K + scol;
  const u16* gB1 = Bt + (size_t)(tn + (w * 2 + 1) * 16 + srow) * K + scol;
  const int cA0 = (w * 2) * 512, cA1 = (w * 2 + 1) * 512;

  const int nIters = K / 32;
#define STAGE2(buf, k0)                               \
  do {                                                \
    gld_lds16(gA0 + (k0), sA + (buf)*4096 + cA0);     \
    gld_lds16(gA1 + (k0), sA + (buf)*4096 + cA1);     \
    gld_lds16(gB0 + (k0), sB + (buf)*4096 + cA0);     \
    gld_lds16(gB1 + (k0), sB + (buf)*4096 + cA1);     \
  } while (0)

  STAGE2(0, 0);
  for (int i = 0; i < nIters; ++i) {
    const int cur = i & 1;
    asm volatile("s_waitcnt vmcnt(0)" ::: "memory");  // buf[cur] staged
    __syncthreads();  // all waves done reading buf[cur^1] (iter i-1) + see stage
    if (i + 1 < nIters) STAGE2(cur ^ 1, (i + 1) * 32);  // overlaps compute below
    const u16* bA = sA + cur * 4096;
    const u16* bB = sB + cur * 4096;
    bf16x8 af[4], bfv[4];
#pragma unroll
    for (int mt = 0; mt < 4; ++mt) af[mt] = ld_frag(bA + (mh + mt * 16 + c) * 32 + cg8);
#pragma unroll
    for (int nt = 0; nt < 4; ++nt) bfv[nt] = ld_frag(bB + (nh + nt * 16 + c) * 32 + cg8);
#pragma unroll
    for (int mt = 0; mt < 4; ++mt)
#pragma unroll
      for (int nt = 0; nt < 4; ++nt)
        acc[mt][nt] = __builtin_amdgcn_mfma_f32_16x16x32_bf16(af[mt], bfv[nt], acc[mt][nt], 0, 0, 0);
  }
#undef STAGE2

  if constexpr (EPI == EPI_KQV) {
    const int s = tn >> 10;         // block-uniform: 0=k, 1=q, 2=v
    const int bb = tm >> 10;        // block-uniform batch
    const int tloc0 = tm & 1023;    // t of local row 0
    if (s == 2) {
      // ---- V: LDS transpose -> coalesced (d,t) stores ----
      __syncthreads();  // all K-loop LDS reads complete before overwrite
      u16(*ldsv)[136] = (u16(*)[136])smem;  // [local_d][local_t], 272B rows (16B-aligned)
#pragma unroll
      for (int mt = 0; mt < 4; ++mt) {
#pragma unroll
        for (int nt = 0; nt < 4; ++nt) {
          const int ld = nh + nt * 16 + c;         // local_d 0..127
          const float bcol = bias[tn + ld];
          uint2 pk = {pack_bf2(acc[mt][nt][0] + bcol, acc[mt][nt][1] + bcol),
                      pack_bf2(acc[mt][nt][2] + bcol, acc[mt][nt][3] + bcol)};
          *(uint2*)&ldsv[ld][mh + mt * 16 + q4 * 4] = pk;  // t-consecutive quad
        }
      }
      __syncthreads();
      // 256 threads: 2 per d-row, each copies 64 u16 (8 x int4 at stride 8 u16)
      const int r = tid >> 1, half = tid & 1;
      const int head = ((tn & 1023) >> 6) + (r >> 6);
      const int d = r & 63;
      const size_t base = ((size_t)((bb * 16 + head) * 3 + 2)) << 16;
      u16* dst = (u16*)outp + base + (size_t)d * 1024 + tloc0 + half * 64;
      const u16* srcr = &ldsv[r][half * 64];
#pragma unroll
      for (int k = 0; k < 8; ++k)
        *(int4*)(dst + k * 8) = *(const int4*)(srcr + k * 8);
    } else {
      // ---- K/Q: (t,d) layout, 32B-run scalar stores (unchanged) ----
      const float scale = (s == 0) ? 0.18033688011112042f : 1.0f;  // 0.125*log2e
#pragma unroll
      for (int mt = 0; mt < 4; ++mt) {
#pragma unroll
        for (int nt = 0; nt < 4; ++nt) {
          const int ld = nh + nt * 16 + c;
          const int hh = ((tn & 1023) >> 6) + (ld >> 6);
          const int d = ld & 63;
          const float bcol = bias[tn + ld];
          const size_t base = ((size_t)((bb * 16 + hh) * 3 + s)) << 16;
#pragma unroll
          for (int rg = 0; rg < 4; ++rg) {
            const int t = tloc0 + mh + mt * 16 + q4 * 4 + rg;
            const float val = (acc[mt][nt][rg] + bcol) * scale;
            ((u16*)outp)[base + (size_t)t * 64 + d] = f2bf(val);
          }
        }
      }
    }
  } else {
    gemm_epilogue<EPI>(acc, bias, outp, resid, N, tm, tn, mh, nh, q4, c);
  }
}

// ---------------------------------------------------------------------------
// GEMM body WIDE (256x128 tile, 8 waves, BK=64, 3-deep ring, 144KB LDS).
// Round-5 loop (best known): counted vmcnt(6), single barrier-pair per K-step,
// conflicts=0 (row-XOR swizzle both-sides). Requires K/64 >= 3, nwg % 8 == 0.
// Best at <=2 block-rounds/CU (gelu/resid/add); loses to body2 at high TLP.
// ---------------------------------------------------------------------------
template <int EPI>
DEVINL void gemm_bodyW(const u16* __restrict__ A, const u16* __restrict__ Bt,
                       const float* __restrict__ bias, void* __restrict__ outp,
                       const float* __restrict__ resid, int N, int K,
                       int tm, int tn) {
  __shared__ alignas(16) u16 sT[3][48 * 512];
  const int tid = threadIdx.x;
  const int w = tid >> 6, l = tid & 63;
  const int q4 = l >> 4, c = l & 15;
  const int mh = (w >> 1) * 64, nh = (w & 1) * 64;  // 4M x 2N waves of 64x64

  f32x4 acc[4][4] = {};

  const int lr = l >> 3;
  const int lc = ((l & 7) ^ lr) * 8;  // pre-swizzled global k-offset (elems)
  const u16* gA[4];
  const u16* gB[2];
#pragma unroll
  for (int j = 0; j < 4; ++j) gA[j] = A + (size_t)(tm + 32 * w + j * 8 + lr) * K + lc;
#pragma unroll
  for (int j = 0; j < 2; ++j) gB[j] = Bt + (size_t)(tn + 16 * w + j * 8 + lr) * K + lc;

  auto stageW = [&](int buf, int k0) {
#pragma unroll
    for (int j = 0; j < 4; ++j) gld_lds16(gA[j] + k0, &sT[buf][(4 * w + j) * 512]);
#pragma unroll
    for (int j = 0; j < 2; ++j) gld_lds16(gB[j] + k0, &sT[buf][(32 + 2 * w + j) * 512]);
  };

  auto computeW = [&](int cur) {
    const u16* bufA = sT[cur];
    const u16* bufB = sT[cur] + 32 * 512;
#pragma unroll
    for (int kh = 0; kh < 2; ++kh) {
      bf16x8 af[4], bfv[4];
#pragma unroll
      for (int mt = 0; mt < 4; ++mt) {
        const int row = mh + mt * 16 + c;
        af[mt] = ld_frag(bufA + row * 64 + ((kh * 4 + q4) ^ (c & 7)) * 8);
      }
#pragma unroll
      for (int nt = 0; nt < 4; ++nt) {
        const int row = nh + nt * 16 + c;
        bfv[nt] = ld_frag(bufB + row * 64 + ((kh * 4 + q4) ^ (c & 7)) * 8);
      }
      __builtin_amdgcn_s_setprio(1);
#pragma unroll
      for (int mt = 0; mt < 4; ++mt)
#pragma unroll
        for (int nt = 0; nt < 4; ++nt)
          acc[mt][nt] = __builtin_amdgcn_mfma_f32_16x16x32_bf16(af[mt], bfv[nt], acc[mt][nt], 0, 0, 0);
      __builtin_amdgcn_s_setprio(0);
    }
  };

  const int nI = K / 64;  // >= 3 required
  stageW(0, 0);
  stageW(1, 64);
  int bc = 0;  // buffer being computed; stage target = (bc+2)%3
  int i = 0;
  for (; i < nI - 1; ++i) {
    asm volatile("s_waitcnt vmcnt(6)" ::: "memory");
    __builtin_amdgcn_s_barrier();
    asm volatile("" ::: "memory");
    if (i + 2 < nI) {
      const int tgt = (bc >= 1) ? bc - 1 : 2;  // (bc+2)%3
      stageW(tgt, (i + 2) * 64);
    }
    computeW(bc);
    bc = (bc < 2) ? bc + 1 : 0;
  }
  asm volatile("s_waitcnt vmcnt(0)" ::: "memory");
  __builtin_amdgcn_s_barrier();
  asm volatile("" ::: "memory");
  computeW(bc);

  gemm_epilogue<EPI>(acc, bias, outp, resid, N, tm, tn, mh, nh, q4, c);
}

// ---- wrappers (distinct names so rocprof attributes per GEMM instance) ----
__global__ __launch_bounds__(256)
void gemm_kqv(const u16* __restrict__ A, const u16* __restrict__ Bt,
              const float* __restrict__ bias, u16* __restrict__ outp,
              int M, int N, int K) {
  int tm, tn;
  xcd_tile(tm, tn);
  gemm_body2<EPI_KQV>(A, Bt, bias, outp, nullptr, M, N, K, tm, tn);
}

__global__ __launch_bounds__(512)
void gemm_gelu(const u16* __restrict__ A, const u16* __restrict__ Bt,
               const float* __restrict__ bias, u16* __restrict__ outp,
               int M, int N, int K) {
  int tm, tn;
  xcd_tile_wide(tm, tn);
  gemm_bodyW<EPI_GELU>(A, Bt, bias, outp, nullptr, N, K, tm, tn);
}

__global__ __launch_bounds__(512)
void gemm_resid(const u16* __restrict__ A, const u16* __restrict__ Bt,
                const float* __restrict__ bias, float* __restrict__ outp,
                const float* __restrict__ resid, int M, int N, int K) {
  int tm, tn;
  xcd_tile_wide(tm, tn);
  gemm_bodyW<EPI_RESID>(A, Bt, bias, outp, resid, N, K, tm, tn);
}

__global__ __launch_bounds__(512)
void gemm_add(const u16* __restrict__ A, const u16* __restrict__ Bt,
              const float* __restrict__ bias, float* __restrict__ outp,
              int M, int N, int K) {
  int tm, tn;
  xcd_tile_wide(tm, tn);
  gemm_bodyW<EPI_ADD>(A, Bt, bias, outp, nullptr, N, K, tm, tn);
}

// ---------------------------------------------------------------------------
// Flash attention, causal, fixed-max softmax in exp2 domain — 128-row Q-tiles.
// r8-verified (−17 µs vs 64-row): K/V staged once per 128 Q-rows; causal
// threshold thr = il + it*128 - jt*64; wave-uniform diagonal skip.
// ---------------------------------------------------------------------------
__global__ __launch_bounds__(512)
void attn_kernel(const u16* __restrict__ kqv, u16* __restrict__ outp) {
  constexpr int LS = 72;  // padded stride: 144B rows, 16B aligned, 2-way max conflicts
  __shared__ alignas(16) u16 sP[128 * LS];  // Q tile at start, then P (aliased)
  __shared__ alignas(16) u16 sK[64 * LS];
  __shared__ alignas(16) u16 sV[64 * LS];   // V^T tile: row=d, col=j
  const int bh = blockIdx.x;
  const int it = (int)gridDim.y - 1 - (int)blockIdx.y;  // longest blocks dispatch first
  const int tid = threadIdx.x;
  const int w = tid >> 6, l = tid & 63, q4 = l >> 4, c = l & 15;
  const int il = w * 16 + c;  // this lane's i-row within the 128-row tile
  const size_t hb = (size_t)bh * 3 * 65536;
  const u16* qbase = kqv + hb;               // flash-Q (T,D), pre-scaled
  const u16* kbase = kqv + hb + 65536;       // flash-K (T,D)
  const u16* vbase = kqv + hb + 2 * 65536;   // V^T (D,T)

  // stage 128-row Q tile into sP (aliased; consumed once after first barrier)
  const int sr = tid >> 3, sc = (tid & 7) * 8;   // 512 threads: rows 0..63 (+64)
  *(int4*)&sP[sr * LS + sc] = *(const int4*)(qbase + (size_t)(it * 128 + sr) * 64 + sc);
  *(int4*)&sP[(sr + 64) * LS + sc] =
      *(const int4*)(qbase + (size_t)(it * 128 + sr + 64) * 64 + sc);

  f32x4 oacc[4] = {};   // O^T: oacc[dt][rg] = O[i=il][d=dt*16+q4*4+rg]
  float lsum = 0.f;     // per-lane partial row-sum for row i=il
  bf16x8 bq0, bq1;      // loop-invariant Q B-frags (lane's own row)

  const int jtMax = 2 * it + 1;
  for (int jt = 0; jt <= jtMax; ++jt) {
    if (jt) __syncthreads();  // prior iter's sK/sV reads done before overwrite
    *(int4*)&sK[sr * LS + sc] = *(const int4*)(kbase + (size_t)(jt * 64 + sr) * 64 + sc);
    *(int4*)&sV[sr * LS + sc] = *(const int4*)(vbase + (size_t)sr * 1024 + jt * 64 + sc);
    __syncthreads();
    if (jt == 0) {  // Q frags: B[k=d][n=i]: lane reads fQ[i=il][d=q4*8..]
      bq0 = ld_frag(sP + il * LS + q4 * 8);
      bq1 = ld_frag(sP + il * LS + 32 + q4 * 8);
    }

    // wave-uniform skip: all 16 rows of this wave above the diagonal
    if (jt * 64 > it * 128 + w * 16 + 15) continue;

    // S^T = fK @ fQ^T: st[nt] row j=nt*16+q4*4+rg, col i=il (log2 domain)
    f32x4 st[4] = {};
#pragma unroll
    for (int nt = 0; nt < 4; ++nt) {
      st[nt] = __builtin_amdgcn_mfma_f32_16x16x32_bf16(
          ld_frag(sK + (nt * 16 + c) * LS + q4 * 8), bq0, st[nt], 0, 0, 0);
      st[nt] = __builtin_amdgcn_mfma_f32_16x16x32_bf16(
          ld_frag(sK + (nt * 16 + c) * LS + 32 + q4 * 8), bq1, st[nt], 0, 0, 0);
    }

    // softmax numerators + P write (rows wave-private; no barrier needed)
    const bool diag = (jt >= 2 * it);             // only last two tiles can mask
    const int thr = il + it * 128 - jt * 64;      // mask j-local > thr
    u16* prow = sP + il * LS;
#pragma unroll
    for (int nt = 0; nt < 4; ++nt) {
      float e0 = __builtin_amdgcn_exp2f(st[nt][0]);
      float e1 = __builtin_amdgcn_exp2f(st[nt][1]);
      float e2 = __builtin_amdgcn_exp2f(st[nt][2]);
      float e3 = __builtin_amdgcn_exp2f(st[nt][3]);
      if (diag) {  // mask j > i: j-local = nt*16+q4*4+rg
        const int jb = nt * 16 + q4 * 4;
        e0 = (jb + 0 > thr) ? 0.f : e0;
        e1 = (jb + 1 > thr) ? 0.f : e1;
        e2 = (jb + 2 > thr) ? 0.f : e2;
        e3 = (jb + 3 > thr) ? 0.f : e3;
      }
      lsum += (e0 + e1) + (e2 + e3);
      uint2 pk = {pack_bf2(e0, e1), pack_bf2(e2, e3)};
      *(uint2*)&prow[nt * 16 + q4 * 4] = pk;
    }

    // O^T += V^T @ P^T: A = V^T-frag (sV row d), B = P-frag (sP row i=il)
    bf16x8 bp0 = ld_frag(sP + il * LS + q4 * 8);
    bf16x8 bp1 = ld_frag(sP + il * LS + 32 + q4 * 8);
#pragma unroll
    for (int dt = 0; dt < 4; ++dt) {
      oacc[dt] = __builtin_amdgcn_mfma_f32_16x16x32_bf16(
          ld_frag(sV + (dt * 16 + c) * LS + q4 * 8), bp0, oacc[dt], 0, 0, 0);
      oacc[dt] = __builtin_amdgcn_mfma_f32_16x16x32_bf16(
          ld_frag(sV + (dt * 16 + c) * LS + 32 + q4 * 8), bp1, oacc[dt], 0, 0, 0);
    }
  }

  // full row sum for i = il: reduce across the 4 q4-groups (lanes c, c+16, c+32, c+48)
  lsum += __shfl_xor(lsum, 16);
  lsum += __shfl_xor(lsum, 32);
  const float linv = 1.f / lsum;

  // write out[b, t=it*128+il, h*64 + dt*16+q4*4+rg] bf16, packed b64 stores
  const int b_ = bh >> 4, h_ = bh & 15;
  const int t_ = it * 128 + il;
  u16* orow = outp + ((size_t)(b_ * 1024 + t_)) * 1024 + h_ * 64;
#pragma unroll
  for (int dt = 0; dt < 4; ++dt) {
    uint2 ok = {pack_bf2(oacc[dt][0] * linv, oacc[dt][1] * linv),
                pack_bf2(oacc[dt][2] * linv, oacc[dt][3] * linv)};
    *(uint2*)&orow[dt * 16 + q4 * 4] = ok;
  }
}

// ---------------------------------------------------------------------------
// Launch
// ---------------------------------------------------------------------------
extern "C" void kernel_launch(void* const* d_in, const int* in_sizes, int n_in,
                              void* d_out, int out_size, void* d_ws, size_t ws_size,
                              hipStream_t stream) {
  const float* x       = (const float*)d_in[0];
  const float* ln1_g   = (const float*)d_in[1];
  const float* ln1_b   = (const float*)d_in[2];
  const float* attn_w  = (const float*)d_in[3];
  const float* attn_b  = (const float*)d_in[4];
  const float* attn_pw = (const float*)d_in[5];
  const float* attn_pb = (const float*)d_in[6];
  const float* ln2_g   = (const float*)d_in[7];
  const float* ln2_b   = (const float*)d_in[8];
  const float* fc_w    = (const float*)d_in[9];
  const float* fc_b    = (const float*)d_in[10];
  const float* mlp_w   = (const float*)d_in[11];
  const float* mlp_b   = (const float*)d_in[12];
  float* out = (float*)d_out;

  // workspace layout (bf16 elements)
  u16* ws = (u16*)d_ws;
  u16* mlpT     = ws;                         // 1024*4096
  u16* attn_wT  = mlpT + 1024 * 4096;         // 3072*1024
  u16* attn_pwT = attn_wT + 3072 * 1024;      // 1024*1024
  u16* fcT      = attn_pwT + 1024 * 1024;     // 4096*1024
  u16* hbuf     = fcT + 4096 * 1024;          // 8192*1024
  u16* kqv      = hbuf + 8192 * 1024;         // 8192*3072 (per-head layout)
  u16* attn_o   = kqv + (size_t)8192 * 3072;  // 8192*1024
  u16* mbuf     = kqv;                        // 8192*4096 (reuses kqv+attn_o)

  dim3 tb(32, 8);
  transpose_bf16<<<dim3(96, 32),  tb, 0, stream>>>(attn_w,  attn_wT,  1024, 3072);
  transpose_bf16<<<dim3(32, 32),  tb, 0, stream>>>(attn_pw, attn_pwT, 1024, 1024);
  transpose_bf16<<<dim3(128, 32), tb, 0, stream>>>(fc_w,    fcT,      1024, 4096);
  transpose_bf16<<<dim3(32, 128), tb, 0, stream>>>(mlp_w,   mlpT,     4096, 1024);

  ln_kernel<<<8192, 256, 0, stream>>>(x, ln1_g, ln1_b, hbuf);

  gemm_kqv<<<dim3(24, 64), 256, 0, stream>>>(hbuf, attn_wT, attn_b, kqv, 8192, 3072, 1024);

  attn_kernel<<<dim3(128, 8), 512, 0, stream>>>(kqv, attn_o);

  gemm_resid<<<dim3(8, 32), 512, 0, stream>>>(attn_o, attn_pwT, attn_pb, out, x,
                                              8192, 1024, 1024);

  ln_kernel<<<8192, 256, 0, stream>>>(out, ln2_g, ln2_b, hbuf);

  gemm_gelu<<<dim3(32, 32), 512, 0, stream>>>(hbuf, fcT, fc_b, mbuf, 8192, 4096, 1024);

  gemm_add<<<dim3(8, 32), 512, 0, stream>>>(mbuf, mlpT, mlp_b, out, 8192, 1024, 4096);
}

// Round 11
// 418.103 us; speedup vs baseline: 1.1194x; 1.0346x over previous
//
#include <hip/hip_runtime.h>
#include <stdint.h>

typedef unsigned short u16;
typedef __bf16 bf16x8 __attribute__((ext_vector_type(8)));
typedef float f32x4 __attribute__((ext_vector_type(4)));

#define DEVINL static __device__ __forceinline__

// fp32 -> bf16 round-to-nearest-even
DEVINL u16 f2bf(float f) {
  uint32_t u = __builtin_bit_cast(uint32_t, f);
  u += 0x7fffu + ((u >> 16) & 1u);
  return (u16)(u >> 16);
}

// pack two fp32 -> bf16x2 dword (round-half-up: +0x8000 then take hi16)
DEVINL uint32_t pack_bf2(float f0, float f1) {
  uint32_t u0 = __builtin_bit_cast(uint32_t, f0) + 0x8000u;
  uint32_t u1 = __builtin_bit_cast(uint32_t, f1) + 0x8000u;
  return __builtin_amdgcn_perm(u1, u0, 0x07060302u);  // [u1.hi16, u0.hi16]
}

DEVINL bf16x8 ld_frag(const u16* p) { return *(const bf16x8*)p; }

DEVINL void gld_lds16(const void* g, void* l) {
  __builtin_amdgcn_global_load_lds((const __attribute__((address_space(1))) void*)g,
                                   (__attribute__((address_space(3))) void*)l, 16, 0, 0);
}

DEVINL int swz4(int r) { return (r & 3) ^ ((r >> 2) & 3); }

// T1: bijective XCD-chunked swizzle, 128-row tiles (body2 grids, nwg % 8 == 0).
DEVINL void xcd_tile(int& tm, int& tn) {
  const int gx = gridDim.x;
  const int flat = blockIdx.x + gx * blockIdx.y;
  const int q = (gx * gridDim.y) >> 3;
  const int wg = (flat & 7) * q + (flat >> 3);
  tn = (wg % gx) * 128;
  tm = (wg / gx) * 128;
}

// T1 for 256-row x 128-col tiles (bodyW grids).
DEVINL void xcd_tile_wide(int& tm, int& tn) {
  const int gx = gridDim.x;
  const int flat = blockIdx.x + gx * blockIdx.y;
  const int q = (gx * gridDim.y) >> 3;
  const int wg = (flat & 7) * q + (flat >> 3);
  tn = (wg % gx) * 128;
  tm = (wg / gx) * 256;
}

// T1 for 256x256 tiles (bodyX grids).
DEVINL void xcd_tile_256(int& tm, int& tn) {
  const int gx = gridDim.x;
  const int flat = blockIdx.x + gx * blockIdx.y;
  const int q = (gx * gridDim.y) >> 3;
  const int wg = (flat & 7) * q + (flat >> 3);
  tn = (wg % gx) * 256;
  tm = (wg / gx) * 256;
}

// ---------------------------------------------------------------------------
// Fused weight convert+transpose: all 4 weights in ONE launch (gap removal).
// Flat grid decode; each block does a 32x32 tile, body identical to the
// r0-proven transpose_bf16.
// ---------------------------------------------------------------------------
__global__ __launch_bounds__(256)
void transpose_all(const float* __restrict__ w0, const float* __restrict__ w1,
                   const float* __restrict__ w2, const float* __restrict__ w3,
                   u16* __restrict__ o0, u16* __restrict__ o1,
                   u16* __restrict__ o2, u16* __restrict__ o3) {
  int id = blockIdx.x;
  const float* W;
  u16* Wt;
  int K, N, xt;
  if (id < 3072)      { W = w0; Wt = o0; K = 1024; N = 3072; xt = 96;            }
  else if (id < 4096) { W = w1; Wt = o1; K = 1024; N = 1024; xt = 32; id -= 3072; }
  else if (id < 8192) { W = w2; Wt = o2; K = 1024; N = 4096; xt = 128; id -= 4096; }
  else                { W = w3; Wt = o3; K = 4096; N = 1024; xt = 32; id -= 8192; }
  const int n0 = (id % xt) * 32, k0 = (id / xt) * 32;
  __shared__ float tile[32][33];
  const int tx = threadIdx.x, ty = threadIdx.y;  // (32,8)
#pragma unroll
  for (int i = 0; i < 32; i += 8)
    tile[ty + i][tx] = W[(size_t)(k0 + ty + i) * N + n0 + tx];
  __syncthreads();
#pragma unroll
  for (int i = 0; i < 32; i += 8)
    Wt[(size_t)(n0 + ty + i) * K + k0 + tx] = f2bf(tile[tx][ty + i]);
}

// ---------------------------------------------------------------------------
// LayerNorm: fp32 (rows,1024) -> bf16, single pass (E[x^2]-mu^2), eps=1e-5
// ---------------------------------------------------------------------------
__global__ __launch_bounds__(256)
void ln_kernel(const float* __restrict__ x, const float* __restrict__ g,
               const float* __restrict__ b, u16* __restrict__ out) {
  __shared__ float red[8];
  const size_t row = blockIdx.x;
  const int tid = threadIdx.x;
  float4 v = ((const float4*)(x + row * 1024))[tid];
  float s = v.x + v.y + v.z + v.w;
  float s2 = v.x * v.x + v.y * v.y + v.z * v.z + v.w * v.w;
#pragma unroll
  for (int o = 32; o; o >>= 1) { s += __shfl_down(s, o); s2 += __shfl_down(s2, o); }
  const int w = tid >> 6;
  if ((tid & 63) == 0) { red[w * 2] = s; red[w * 2 + 1] = s2; }
  __syncthreads();
  const float S = red[0] + red[2] + red[4] + red[6];
  const float S2 = red[1] + red[3] + red[5] + red[7];
  const float mu = S * (1.f / 1024.f);
  const float var = S2 * (1.f / 1024.f) - mu * mu;
  const float rstd = rsqrtf(var + 1e-5f);
  float4 gv = ((const float4*)g)[tid];
  float4 bv = ((const float4*)b)[tid];
  ushort4 o;
  o.x = f2bf((v.x - mu) * rstd * gv.x + bv.x);
  o.y = f2bf((v.y - mu) * rstd * gv.y + bv.y);
  o.z = f2bf((v.z - mu) * rstd * gv.z + bv.z);
  o.w = f2bf((v.w - mu) * rstd * gv.w + bv.w);
  ((ushort4*)(out + row * 1024))[tid] = o;
}

// ---------------------------------------------------------------------------
// Shared epilogue: C row/col scatter with fused ops (bodyW users).
// ---------------------------------------------------------------------------
enum { EPI_KQV = 0, EPI_RESID = 1, EPI_GELU = 2, EPI_ADD = 3 };

template <int EPI>
DEVINL void gemm_epilogue(f32x4 (&acc)[4][4], const float* __restrict__ bias,
                          void* __restrict__ outp, const float* __restrict__ resid,
                          int N, int tm, int tn, int mh, int nh, int q4, int c) {
#pragma unroll
  for (int mt = 0; mt < 4; ++mt) {
#pragma unroll
    for (int nt = 0; nt < 4; ++nt) {
      const int col = tn + nh + nt * 16 + c;
      const float bcol = bias[col];
#pragma unroll
      for (int rg = 0; rg < 4; ++rg) {
        const int row = tm + mh + mt * 16 + q4 * 4 + rg;
        float val = acc[mt][nt][rg] + bcol;
        if constexpr (EPI == EPI_RESID) {
          const size_t idx = (size_t)row * 1024 + col;
          ((float*)outp)[idx] = val + resid[idx];
        } else if constexpr (EPI == EPI_GELU) {
          const float x2 = val * val;
          const float t = __builtin_fmaf(x2, -0.102952445f, -2.30221235f);
          const float e = __builtin_amdgcn_exp2f(val * t);
          const float ge = val * __builtin_amdgcn_rcpf(1.0f + e);
          ((u16*)outp)[(size_t)row * N + col] = f2bf(ge);
        } else {  // EPI_ADD
          const size_t idx = (size_t)row * 1024 + col;
          ((float*)outp)[idx] += val;
        }
      }
    }
  }
}

// ---------------------------------------------------------------------------
// GEMM body2 (128x128, 4 waves, 2-buffer) — KQV only, with the r10-verified
// split epilogue (LDS-transposed coalesced V stores).
// ---------------------------------------------------------------------------
template <int EPI>
DEVINL void gemm_body2(const u16* __restrict__ A, const u16* __restrict__ Bt,
                       const float* __restrict__ bias, void* __restrict__ outp,
                       const float* __restrict__ resid, int M, int N, int K,
                       int tm, int tn) {
  __shared__ alignas(16) u16 smem[17408];  // 34.8KB; K-loop uses first 32KB
  u16* sA = smem;          // [2][128*32]
  u16* sB = smem + 8192;   // [2][128*32]
  const int tid = threadIdx.x;
  const int w = tid >> 6, l = tid & 63;
  const int q4 = l >> 4, c = l & 15;
  const int mh = (w >> 1) * 64, nh = (w & 1) * 64;
  const int cg8 = (q4 ^ swz4(c)) * 8;

  f32x4 acc[4][4] = {};

  const int srow = l >> 2;
  const int scol = ((l & 3) ^ swz4(srow)) * 8;
  const u16* gA0 = A + (size_t)(tm + (w * 2) * 16 + srow) * K + scol;
  const u16* gA1 = A + (size_t)(tm + (w * 2 + 1) * 16 + srow) * K + scol;
  const u16* gB0 = Bt + (size_t)(tn + (w * 2) * 16 + srow) * K + scol;
  const u16* gB1 = Bt + (size_t)(tn + (w * 2 + 1) * 16 + srow) * K + scol;
  const int cA0 = (w * 2) * 512, cA1 = (w * 2 + 1) * 512;

  const int nIters = K / 32;
#define STAGE2(buf, k0)                               \
  do {                                                \
    gld_lds16(gA0 + (k0), sA + (buf)*4096 + cA0);     \
    gld_lds16(gA1 + (k0), sA + (buf)*4096 + cA1);     \
    gld_lds16(gB0 + (k0), sB + (buf)*4096 + cA0);     \
    gld_lds16(gB1 + (k0), sB + (buf)*4096 + cA1);     \
  } while (0)

  STAGE2(0, 0);
  for (int i = 0; i < nIters; ++i) {
    const int cur = i & 1;
    asm volatile("s_waitcnt vmcnt(0)" ::: "memory");  // buf[cur] staged
    __syncthreads();
    if (i + 1 < nIters) STAGE2(cur ^ 1, (i + 1) * 32);
    const u16* bA = sA + cur * 4096;
    const u16* bB = sB + cur * 4096;
    bf16x8 af[4], bfv[4];
#pragma unroll
    for (int mt = 0; mt < 4; ++mt) af[mt] = ld_frag(bA + (mh + mt * 16 + c) * 32 + cg8);
#pragma unroll
    for (int nt = 0; nt < 4; ++nt) bfv[nt] = ld_frag(bB + (nh + nt * 16 + c) * 32 + cg8);
#pragma unroll
    for (int mt = 0; mt < 4; ++mt)
#pragma unroll
      for (int nt = 0; nt < 4; ++nt)
        acc[mt][nt] = __builtin_amdgcn_mfma_f32_16x16x32_bf16(af[mt], bfv[nt], acc[mt][nt], 0, 0, 0);
  }
#undef STAGE2

  if constexpr (EPI == EPI_KQV) {
    const int s = tn >> 10;         // block-uniform: 0=k, 1=q, 2=v
    const int bb = tm >> 10;        // block-uniform batch
    const int tloc0 = tm & 1023;    // t of local row 0
    if (s == 2) {
      // ---- V: LDS transpose -> coalesced (d,t) stores ----
      __syncthreads();
      u16(*ldsv)[136] = (u16(*)[136])smem;
#pragma unroll
      for (int mt = 0; mt < 4; ++mt) {
#pragma unroll
        for (int nt = 0; nt < 4; ++nt) {
          const int ld = nh + nt * 16 + c;
          const float bcol = bias[tn + ld];
          uint2 pk = {pack_bf2(acc[mt][nt][0] + bcol, acc[mt][nt][1] + bcol),
                      pack_bf2(acc[mt][nt][2] + bcol, acc[mt][nt][3] + bcol)};
          *(uint2*)&ldsv[ld][mh + mt * 16 + q4 * 4] = pk;
        }
      }
      __syncthreads();
      const int r = tid >> 1, half = tid & 1;
      const int head = ((tn & 1023) >> 6) + (r >> 6);
      const int d = r & 63;
      const size_t base = ((size_t)((bb * 16 + head) * 3 + 2)) << 16;
      u16* dst = (u16*)outp + base + (size_t)d * 1024 + tloc0 + half * 64;
      const u16* srcr = &ldsv[r][half * 64];
#pragma unroll
      for (int k = 0; k < 8; ++k)
        *(int4*)(dst + k * 8) = *(const int4*)(srcr + k * 8);
    } else {
      const float scale = (s == 0) ? 0.18033688011112042f : 1.0f;  // 0.125*log2e
#pragma unroll
      for (int mt = 0; mt < 4; ++mt) {
#pragma unroll
        for (int nt = 0; nt < 4; ++nt) {
          const int ld = nh + nt * 16 + c;
          const int hh = ((tn & 1023) >> 6) + (ld >> 6);
          const int d = ld & 63;
          const float bcol = bias[tn + ld];
          const size_t base = ((size_t)((bb * 16 + hh) * 3 + s)) << 16;
#pragma unroll
          for (int rg = 0; rg < 4; ++rg) {
            const int t = tloc0 + mh + mt * 16 + q4 * 4 + rg;
            const float val = (acc[mt][nt][rg] + bcol) * scale;
            ((u16*)outp)[base + (size_t)t * 64 + d] = f2bf(val);
          }
        }
      }
    }
  } else {
    gemm_epilogue<EPI>(acc, bias, outp, resid, N, tm, tn, mh, nh, q4, c);
  }
}

// ---------------------------------------------------------------------------
// GEMM body WIDE (256x128 tile, 8 waves, BK=64, 3-deep ring, 144KB LDS).
// Round-5 loop (best known for N=1024 shapes): counted vmcnt(6), single
// barrier-pair per K-step, conflicts=0. Used by resid/add.
// ---------------------------------------------------------------------------
template <int EPI>
DEVINL void gemm_bodyW(const u16* __restrict__ A, const u16* __restrict__ Bt,
                       const float* __restrict__ bias, void* __restrict__ outp,
                       const float* __restrict__ resid, int N, int K,
                       int tm, int tn) {
  __shared__ alignas(16) u16 sT[3][48 * 512];
  const int tid = threadIdx.x;
  const int w = tid >> 6, l = tid & 63;
  const int q4 = l >> 4, c = l & 15;
  const int mh = (w >> 1) * 64, nh = (w & 1) * 64;

  f32x4 acc[4][4] = {};

  const int lr = l >> 3;
  const int lc = ((l & 7) ^ lr) * 8;
  const u16* gA[4];
  const u16* gB[2];
#pragma unroll
  for (int j = 0; j < 4; ++j) gA[j] = A + (size_t)(tm + 32 * w + j * 8 + lr) * K + lc;
#pragma unroll
  for (int j = 0; j < 2; ++j) gB[j] = Bt + (size_t)(tn + 16 * w + j * 8 + lr) * K + lc;

  auto stageW = [&](int buf, int k0) {
#pragma unroll
    for (int j = 0; j < 4; ++j) gld_lds16(gA[j] + k0, &sT[buf][(4 * w + j) * 512]);
#pragma unroll
    for (int j = 0; j < 2; ++j) gld_lds16(gB[j] + k0, &sT[buf][(32 + 2 * w + j) * 512]);
  };

  auto computeW = [&](int cur) {
    const u16* bufA = sT[cur];
    const u16* bufB = sT[cur] + 32 * 512;
#pragma unroll
    for (int kh = 0; kh < 2; ++kh) {
      bf16x8 af[4], bfv[4];
#pragma unroll
      for (int mt = 0; mt < 4; ++mt) {
        const int row = mh + mt * 16 + c;
        af[mt] = ld_frag(bufA + row * 64 + ((kh * 4 + q4) ^ (c & 7)) * 8);
      }
#pragma unroll
      for (int nt = 0; nt < 4; ++nt) {
        const int row = nh + nt * 16 + c;
        bfv[nt] = ld_frag(bufB + row * 64 + ((kh * 4 + q4) ^ (c & 7)) * 8);
      }
      __builtin_amdgcn_s_setprio(1);
#pragma unroll
      for (int mt = 0; mt < 4; ++mt)
#pragma unroll
        for (int nt = 0; nt < 4; ++nt)
          acc[mt][nt] = __builtin_amdgcn_mfma_f32_16x16x32_bf16(af[mt], bfv[nt], acc[mt][nt], 0, 0, 0);
      __builtin_amdgcn_s_setprio(0);
    }
  };

  const int nI = K / 64;  // >= 3 required
  stageW(0, 0);
  stageW(1, 64);
  int bc = 0;
  int i = 0;
  for (; i < nI - 1; ++i) {
    asm volatile("s_waitcnt vmcnt(6)" ::: "memory");
    __builtin_amdgcn_s_barrier();
    asm volatile("" ::: "memory");
    if (i + 2 < nI) {
      const int tgt = (bc >= 1) ? bc - 1 : 2;
      stageW(tgt, (i + 2) * 64);
    }
    computeW(bc);
    bc = (bc < 2) ? bc + 1 : 0;
  }
  asm volatile("s_waitcnt vmcnt(0)" ::: "memory");
  __builtin_amdgcn_s_barrier();
  asm volatile("" ::: "memory");
  computeW(bc);

  gemm_epilogue<EPI>(acc, bias, outp, resid, N, tm, tn, mh, nh, q4, c);
}

// ---------------------------------------------------------------------------
// GEMM body X (256x256 tile, 8 waves, BK=32, 4-deep ring, 128KB LDS) — GELU.
// Control flow is the r2/r3-PROVEN gemm_body4 ring (prologue stage 0,1,2;
// vmcnt(8) steady, 4/0 tail; barrier; stage i+3; compute), with 2x A-panel
// reuse: per-MFMA LDS reads 512->384B (-25%), staging 192->128B (-33%),
// barriers/MFMA unchanged. Wave w -> (wr=w>>2 of 2) x (wc=w&3 of 4); each
// wave owns 128x64 output (acc[8][4]). Stage chunks: 1KB = 16 rows x 64B;
// wave w stages A rows (w*2+j)*16.. and B rows likewise (2+2 loads/thread).
// Swizzle: 64B rows, 4 col-groups; cg ^ (row&3) both-sides (balanced
// 8 dwords/bank, same proof as body2/W). Requires K/32 >= 3, nwg % 8 == 0.
// ---------------------------------------------------------------------------
template <int EPI>
DEVINL void gemm_bodyX(const u16* __restrict__ A, const u16* __restrict__ Bt,
                       const float* __restrict__ bias, void* __restrict__ outp,
                       int N, int K, int tm, int tn) {
  __shared__ alignas(16) u16 sX[4][16384];  // per buf: A 256x32 | B 256x32
  const int tid = threadIdx.x;
  const int w = tid >> 6, l = tid & 63;
  const int q4 = l >> 4, c = l & 15;
  const int wr = (w >> 2) * 128, wc = (w & 3) * 64;
  const int ko = (q4 ^ (c & 3)) * 8;  // swizzled frag col offset (elems)

  f32x4 acc[8][4] = {};

  const int lr = l >> 2;                     // 0..15 row within 16-row chunk
  const int lc = ((l & 3) ^ (lr & 3)) * 8;   // pre-swizzled global col (elems)
  const u16* gA0 = A + (size_t)(tm + (w * 2) * 16 + lr) * K + lc;
  const u16* gA1 = A + (size_t)(tm + (w * 2 + 1) * 16 + lr) * K + lc;
  const u16* gB0 = Bt + (size_t)(tn + (w * 2) * 16 + lr) * K + lc;
  const u16* gB1 = Bt + (size_t)(tn + (w * 2 + 1) * 16 + lr) * K + lc;
  const int cA0 = (w * 2) * 512, cA1 = (w * 2 + 1) * 512;

#define STAGEX(buf, k0)                              \
  do {                                               \
    gld_lds16(gA0 + (k0), &sX[buf][cA0]);            \
    gld_lds16(gA1 + (k0), &sX[buf][cA1]);            \
    gld_lds16(gB0 + (k0), &sX[buf][8192 + cA0]);     \
    gld_lds16(gB1 + (k0), &sX[buf][8192 + cA1]);     \
  } while (0)

  auto computeX = [&](int cur) {
    const u16* bufA = sX[cur];
    const u16* bufB = sX[cur] + 8192;
    bf16x8 af[8], bfv[4];
#pragma unroll
    for (int mt = 0; mt < 8; ++mt) af[mt] = ld_frag(bufA + (wr + mt * 16 + c) * 32 + ko);
#pragma unroll
    for (int nt = 0; nt < 4; ++nt) bfv[nt] = ld_frag(bufB + (wc + nt * 16 + c) * 32 + ko);
    __builtin_amdgcn_s_setprio(1);
#pragma unroll
    for (int mt = 0; mt < 8; ++mt)
#pragma unroll
      for (int nt = 0; nt < 4; ++nt)
        acc[mt][nt] = __builtin_amdgcn_mfma_f32_16x16x32_bf16(af[mt], bfv[nt], acc[mt][nt], 0, 0, 0);
    __builtin_amdgcn_s_setprio(0);
  };

  const int nI = K / 32;  // >= 3 required
  STAGEX(0, 0);
  STAGEX(1, 32);
  STAGEX(2, 64);
  int i = 0;
  for (; i < nI - 2; ++i) {
    // own stage-i loads done; <=8 (stages i+1, i+2) remain outstanding
    asm volatile("s_waitcnt vmcnt(8)" ::: "memory");
    __builtin_amdgcn_s_barrier();
    asm volatile("" ::: "memory");
    if (i + 3 < nI) STAGEX((i + 3) & 3, (i + 3) * 32);  // overwrites buf[(i-1)&3]
    computeX(i & 3);
  }
  asm volatile("s_waitcnt vmcnt(4)" ::: "memory");
  __builtin_amdgcn_s_barrier();
  asm volatile("" ::: "memory");
  computeX(i & 3);
  ++i;
  asm volatile("s_waitcnt vmcnt(0)" ::: "memory");
  __builtin_amdgcn_s_barrier();
  asm volatile("" ::: "memory");
  computeX(i & 3);
#undef STAGEX

  // epilogue (GELU): u16 stores, row-major
#pragma unroll
  for (int mt = 0; mt < 8; ++mt) {
#pragma unroll
    for (int nt = 0; nt < 4; ++nt) {
      const int col = tn + wc + nt * 16 + c;
      const float bcol = bias[col];
#pragma unroll
      for (int rg = 0; rg < 4; ++rg) {
        const int row = tm + wr + mt * 16 + q4 * 4 + rg;
        const float val = acc[mt][nt][rg] + bcol;
        const float x2 = val * val;
        const float t = __builtin_fmaf(x2, -0.102952445f, -2.30221235f);
        const float e = __builtin_amdgcn_exp2f(val * t);
        const float ge = val * __builtin_amdgcn_rcpf(1.0f + e);
        ((u16*)outp)[(size_t)row * N + col] = f2bf(ge);
      }
    }
  }
}

// ---- wrappers (distinct names so rocprof attributes per GEMM instance) ----
__global__ __launch_bounds__(256)
void gemm_kqv(const u16* __restrict__ A, const u16* __restrict__ Bt,
              const float* __restrict__ bias, u16* __restrict__ outp,
              int M, int N, int K) {
  int tm, tn;
  xcd_tile(tm, tn);
  gemm_body2<EPI_KQV>(A, Bt, bias, outp, nullptr, M, N, K, tm, tn);
}

__global__ __launch_bounds__(512)
void gemm_gelu(const u16* __restrict__ A, const u16* __restrict__ Bt,
               const float* __restrict__ bias, u16* __restrict__ outp,
               int M, int N, int K) {
  int tm, tn;
  xcd_tile_256(tm, tn);
  gemm_bodyX<EPI_GELU>(A, Bt, bias, outp, N, K, tm, tn);
}

__global__ __launch_bounds__(512)
void gemm_resid(const u16* __restrict__ A, const u16* __restrict__ Bt,
                const float* __restrict__ bias, float* __restrict__ outp,
                const float* __restrict__ resid, int M, int N, int K) {
  int tm, tn;
  xcd_tile_wide(tm, tn);
  gemm_bodyW<EPI_RESID>(A, Bt, bias, outp, resid, N, K, tm, tn);
}

__global__ __launch_bounds__(512)
void gemm_add(const u16* __restrict__ A, const u16* __restrict__ Bt,
              const float* __restrict__ bias, float* __restrict__ outp,
              int M, int N, int K) {
  int tm, tn;
  xcd_tile_wide(tm, tn);
  gemm_bodyW<EPI_ADD>(A, Bt, bias, outp, nullptr, N, K, tm, tn);
}

// ---------------------------------------------------------------------------
// Flash attention, causal, fixed-max softmax in exp2 domain — 128-row Q-tiles.
// r8-verified: K/V staged once per 128 Q-rows; causal threshold
// thr = il + it*128 - jt*64; wave-uniform diagonal skip.
// ---------------------------------------------------------------------------
__global__ __launch_bounds__(512)
void attn_kernel(const u16* __restrict__ kqv, u16* __restrict__ outp) {
  constexpr int LS = 72;
  __shared__ alignas(16) u16 sP[128 * LS];  // Q tile at start, then P (aliased)
  __shared__ alignas(16) u16 sK[64 * LS];
  __shared__ alignas(16) u16 sV[64 * LS];   // V^T tile: row=d, col=j
  const int bh = blockIdx.x;
  const int it = (int)gridDim.y - 1 - (int)blockIdx.y;
  const int tid = threadIdx.x;
  const int w = tid >> 6, l = tid & 63, q4 = l >> 4, c = l & 15;
  const int il = w * 16 + c;
  const size_t hb = (size_t)bh * 3 * 65536;
  const u16* qbase = kqv + hb;
  const u16* kbase = kqv + hb + 65536;
  const u16* vbase = kqv + hb + 2 * 65536;

  const int sr = tid >> 3, sc = (tid & 7) * 8;
  *(int4*)&sP[sr * LS + sc] = *(const int4*)(qbase + (size_t)(it * 128 + sr) * 64 + sc);
  *(int4*)&sP[(sr + 64) * LS + sc] =
      *(const int4*)(qbase + (size_t)(it * 128 + sr + 64) * 64 + sc);

  f32x4 oacc[4] = {};
  float lsum = 0.f;
  bf16x8 bq0, bq1;

  const int jtMax = 2 * it + 1;
  for (int jt = 0; jt <= jtMax; ++jt) {
    if (jt) __syncthreads();
    *(int4*)&sK[sr * LS + sc] = *(const int4*)(kbase + (size_t)(jt * 64 + sr) * 64 + sc);
    *(int4*)&sV[sr * LS + sc] = *(const int4*)(vbase + (size_t)sr * 1024 + jt * 64 + sc);
    __syncthreads();
    if (jt == 0) {
      bq0 = ld_frag(sP + il * LS + q4 * 8);
      bq1 = ld_frag(sP + il * LS + 32 + q4 * 8);
    }

    if (jt * 64 > it * 128 + w * 16 + 15) continue;

    f32x4 st[4] = {};
#pragma unroll
    for (int nt = 0; nt < 4; ++nt) {
      st[nt] = __builtin_amdgcn_mfma_f32_16x16x32_bf16(
          ld_frag(sK + (nt * 16 + c) * LS + q4 * 8), bq0, st[nt], 0, 0, 0);
      st[nt] = __builtin_amdgcn_mfma_f32_16x16x32_bf16(
          ld_frag(sK + (nt * 16 + c) * LS + 32 + q4 * 8), bq1, st[nt], 0, 0, 0);
    }

    const bool diag = (jt >= 2 * it);
    const int thr = il + it * 128 - jt * 64;
    u16* prow = sP + il * LS;
#pragma unroll
    for (int nt = 0; nt < 4; ++nt) {
      float e0 = __builtin_amdgcn_exp2f(st[nt][0]);
      float e1 = __builtin_amdgcn_exp2f(st[nt][1]);
      float e2 = __builtin_amdgcn_exp2f(st[nt][2]);
      float e3 = __builtin_amdgcn_exp2f(st[nt][3]);
      if (diag) {
        const int jb = nt * 16 + q4 * 4;
        e0 = (jb + 0 > thr) ? 0.f : e0;
        e1 = (jb + 1 > thr) ? 0.f : e1;
        e2 = (jb + 2 > thr) ? 0.f : e2;
        e3 = (jb + 3 > thr) ? 0.f : e3;
      }
      lsum += (e0 + e1) + (e2 + e3);
      uint2 pk = {pack_bf2(e0, e1), pack_bf2(e2, e3)};
      *(uint2*)&prow[nt * 16 + q4 * 4] = pk;
    }

    bf16x8 bp0 = ld_frag(sP + il * LS + q4 * 8);
    bf16x8 bp1 = ld_frag(sP + il * LS + 32 + q4 * 8);
#pragma unroll
    for (int dt = 0; dt < 4; ++dt) {
      oacc[dt] = __builtin_amdgcn_mfma_f32_16x16x32_bf16(
          ld_frag(sV + (dt * 16 + c) * LS + q4 * 8), bp0, oacc[dt], 0, 0, 0);
      oacc[dt] = __builtin_amdgcn_mfma_f32_16x16x32_bf16(
          ld_frag(sV + (dt * 16 + c) * LS + 32 + q4 * 8), bp1, oacc[dt], 0, 0, 0);
    }
  }

  lsum += __shfl_xor(lsum, 16);
  lsum += __shfl_xor(lsum, 32);
  const float linv = 1.f / lsum;

  const int b_ = bh >> 4, h_ = bh & 15;
  const int t_ = it * 128 + il;
  u16* orow = outp + ((size_t)(b_ * 1024 + t_)) * 1024 + h_ * 64;
#pragma unroll
  for (int dt = 0; dt < 4; ++dt) {
    uint2 ok = {pack_bf2(oacc[dt][0] * linv, oacc[dt][1] * linv),
                pack_bf2(oacc[dt][2] * linv, oacc[dt][3] * linv)};
    *(uint2*)&orow[dt * 16 + q4 * 4] = ok;
  }
}

// ---------------------------------------------------------------------------
// Launch
// ---------------------------------------------------------------------------
extern "C" void kernel_launch(void* const* d_in, const int* in_sizes, int n_in,
                              void* d_out, int out_size, void* d_ws, size_t ws_size,
                              hipStream_t stream) {
  const float* x       = (const float*)d_in[0];
  const float* ln1_g   = (const float*)d_in[1];
  const float* ln1_b   = (const float*)d_in[2];
  const float* attn_w  = (const float*)d_in[3];
  const float* attn_b  = (const float*)d_in[4];
  const float* attn_pw = (const float*)d_in[5];
  const float* attn_pb = (const float*)d_in[6];
  const float* ln2_g   = (const float*)d_in[7];
  const float* ln2_b   = (const float*)d_in[8];
  const float* fc_w    = (const float*)d_in[9];
  const float* fc_b    = (const float*)d_in[10];
  const float* mlp_w   = (const float*)d_in[11];
  const float* mlp_b   = (const float*)d_in[12];
  float* out = (float*)d_out;

  // workspace layout (bf16 elements)
  u16* ws = (u16*)d_ws;
  u16* mlpT     = ws;                         // 1024*4096
  u16* attn_wT  = mlpT + 1024 * 4096;         // 3072*1024
  u16* attn_pwT = attn_wT + 3072 * 1024;      // 1024*1024
  u16* fcT      = attn_pwT + 1024 * 1024;     // 4096*1024
  u16* hbuf     = fcT + 4096 * 1024;          // 8192*1024
  u16* kqv      = hbuf + 8192 * 1024;         // 8192*3072 (per-head layout)
  u16* attn_o   = kqv + (size_t)8192 * 3072;  // 8192*1024
  u16* mbuf     = kqv;                        // 8192*4096 (reuses kqv+attn_o)

  transpose_all<<<12288, dim3(32, 8), 0, stream>>>(attn_w, attn_pw, fc_w, mlp_w,
                                                   attn_wT, attn_pwT, fcT, mlpT);

  ln_kernel<<<8192, 256, 0, stream>>>(x, ln1_g, ln1_b, hbuf);

  gemm_kqv<<<dim3(24, 64), 256, 0, stream>>>(hbuf, attn_wT, attn_b, kqv, 8192, 3072, 1024);

  attn_kernel<<<dim3(128, 8), 512, 0, stream>>>(kqv, attn_o);

  gemm_resid<<<dim3(8, 32), 512, 0, stream>>>(attn_o, attn_pwT, attn_pb, out, x,
                                              8192, 1024, 1024);

  ln_kernel<<<8192, 256, 0, stream>>>(out, ln2_g, ln2_b, hbuf);

  gemm_gelu<<<dim3(16, 32), 512, 0, stream>>>(hbuf, fcT, fc_b, mbuf, 8192, 4096, 1024);

  gemm_add<<<dim3(8, 32), 512, 0, stream>>>(mbuf, mlpT, mlp_b, out, 8192, 1024, 4096);
}